// Round 6
// baseline (2260.004 us; speedup 1.0000x reference)
//
#include <hip/hip_runtime.h>
#include <hip/hip_bf16.h>

typedef __attribute__((ext_vector_type(8))) short short8;
typedef __attribute__((ext_vector_type(4))) float floatx4;

#define NB 128      // batch N
#define LS 64       // seq L
#define HD 512      // hidden H
#define ED 512      // embed E
#define NH 65536    // NB*HD elements per s-slab
#define LDA 72      // LDS tile stride (64 + 8 pad, keeps 16B alignment)

// ws layout (byte offsets)
#define OFF_WIN    0ull          // W_in bf16   [512*512]
#define OFF_WOUT   524288ull     // W_out bf16  [512*512]
#define OFF_XT     1048576ull    // x_t bf16    [64][128][512]  (= level 0)
#define OFF_LVL0   9437184ull    // level ping  bf16 [64][128][512]
#define OFF_LVL1   17825792ull   // level pong  bf16 [64][128][512]
#define OFF_OUTS   26214400ull   // outs bf16   [64][128][512]
#define OFF_PA     34603008ull   // coef chain ping f32 (up to 5x 512x512)
#define OFF_PB     39845888ull   // coef chain pong f32
#define OFF_BCAT   45088768ull   // Bcat_1..4 bf16 concat (7 MB)
#define OFF_BETA   52428800ull   // beta_1..4 f32 [4][512]
#define OFF_PART   52436992ull   // partials f32 [128]
#define OFF_Y      OFF_LVL0      // Y f32 [8192][512] aliases lvl bufs after recurrence

static __device__ __forceinline__ unsigned short f2b(float f) {
  unsigned u = __float_as_uint(f);
  u += 0x7fffu + ((u >> 16) & 1u);   // round-to-nearest-even
  return (unsigned short)(u >> 16);
}
static __device__ __forceinline__ float b2f(unsigned short h) {
  return __uint_as_float(((unsigned)h) << 16);
}

// load 8 consecutive f32, produce bf16x8 packed; variant 0 = hi, 1 = lo residual
static __device__ __forceinline__ uint4 cvt8(const float* s, int variant) {
  floatx4 f0 = *(const floatx4*)s;
  floatx4 f1 = *(const floatx4*)(s + 4);
  float f[8] = {f0.x, f0.y, f0.z, f0.w, f1.x, f1.y, f1.z, f1.w};
  unsigned short b[8];
#pragma unroll
  for (int k = 0; k < 8; ++k) {
    unsigned short h = f2b(f[k]);
    b[k] = (variant == 0) ? h : f2b(f[k] - b2f(h));
  }
  uint4 u;
  u.x = b[0] | ((unsigned)b[1] << 16); u.y = b[2] | ((unsigned)b[3] << 16);
  u.z = b[4] | ((unsigned)b[5] << 16); u.w = b[6] | ((unsigned)b[7] << 16);
  return u;
}

// ---- shared GEMM core: BM=64, BN=128, BK=64, 256 threads (4 waves, 2x2) ----
__device__ __forceinline__ void gemm_core24(const unsigned short* As, const unsigned short* Bs,
                                            floatx4 acc[2][4], int wm, int wn, int lane) {
  const int rb = lane & 15;
  const int kg = (lane >> 4) * 8;
#pragma unroll
  for (int kk = 0; kk < 64; kk += 32) {
    short8 a[2], b[4];
#pragma unroll
    for (int i = 0; i < 2; ++i)
      a[i] = *(const short8*)&As[(wm * 32 + i * 16 + rb) * LDA + kk + kg];
#pragma unroll
    for (int j = 0; j < 4; ++j)
      b[j] = *(const short8*)&Bs[(wn * 64 + j * 16 + rb) * LDA + kk + kg];
#pragma unroll
    for (int i = 0; i < 2; ++i)
#pragma unroll
      for (int j = 0; j < 4; ++j)
        acc[i][j] = __builtin_amdgcn_mfma_f32_16x16x32_bf16(a[i], b[j], acc[i][j], 0, 0, 0);
  }
}

__device__ __forceinline__ void stageA_bf16(unsigned short* As, const unsigned short* src, int tid) {
  int r = tid >> 3, kc = (tid & 7) * 8;
#pragma unroll
  for (int p = 0; p < 2; ++p)
    *(uint4*)&As[(r + p * 32) * LDA + kc] = *(const uint4*)(src + (size_t)(r + p * 32) * 512 + kc);
}

__device__ __forceinline__ void stageA_emb(unsigned short* As, const float* table,
                                           const int* labels, int m0, int k0, int tid) {
  int r = tid >> 3, kc = (tid & 7) * 8;
#pragma unroll
  for (int p = 0; p < 2; ++p) {
    int row = r + p * 32;
    const float* s = table + (size_t)labels[m0 + row] * ED + k0 + kc;
    *(uint4*)&As[row * LDA + kc] = cvt8(s, 0);
  }
}

__device__ __forceinline__ void stageB(unsigned short* Bs, const unsigned short* src, int ldB, int tid) {
  int r = tid >> 3, kc = (tid & 7) * 8;
#pragma unroll
  for (int p = 0; p < 4; ++p)
    *(uint4*)&Bs[(r + p * 32) * LDA + kc] = *(const uint4*)(src + (size_t)(r + p * 32) * ldB + kc);
}

// ---- phase 1: x_t[l][n][h] = bf16( emb(labels) @ W_in^T + b_in ) ----
__global__ __launch_bounds__(256) void k_gemm_emb(const float* __restrict__ table,
                                                  const int* __restrict__ labels,
                                                  const unsigned short* __restrict__ Wb,
                                                  const float* __restrict__ bias,
                                                  unsigned short* __restrict__ xt) {
  __shared__ unsigned short As[64 * LDA];
  __shared__ unsigned short Bs[128 * LDA];
  int tid = threadIdx.x;
  int mtile = blockIdx.x >> 2, ntile = blockIdx.x & 3;
  int m0 = mtile * 64, n0 = ntile * 128;
  int lane = tid & 63, wave = tid >> 6, wm = wave >> 1, wn = wave & 1;
  floatx4 acc[2][4] = {};
  for (int k0 = 0; k0 < 512; k0 += 64) {
    stageA_emb(As, table, labels, m0, k0, tid);
    stageB(Bs, Wb + (size_t)n0 * 512 + k0, 512, tid);
    __syncthreads();
    gemm_core24(As, Bs, acc, wm, wn, lane);
    __syncthreads();
  }
  int rb = lane & 15, rg = (lane >> 4) * 4;
#pragma unroll
  for (int i = 0; i < 2; ++i)
#pragma unroll
    for (int j = 0; j < 4; ++j) {
      int col = n0 + wn * 64 + j * 16 + rb;
      float bv = bias[col];
#pragma unroll
      for (int reg = 0; reg < 4; ++reg) {
        int m = m0 + wm * 32 + i * 16 + rg + reg;
        int n = m >> 6, l = m & 63;
        xt[((size_t)l * NB + n) * HD + col] = f2b(acc[i][j][reg] + bv);
      }
    }
}

// ---- coefficient chain iteration: P_{m+1,j} = gemm(P_{m,j}, W2) + gemm(P_{m,j-1}, W1)
//      P stored transposed ([k][t] row-major, P = A^T). hi/lo split (3 terms) for ~f32 accuracy. ----
__global__ __launch_bounds__(256) void k_coef(const float* __restrict__ Pin,
                                              float* __restrict__ Pout,
                                              const float* __restrict__ Ws,
                                              int m) {
  __shared__ unsigned short As[64 * LDA];
  __shared__ unsigned short Bs[128 * LDA];
  int tid = threadIdx.x;
  int j = blockIdx.x >> 5, tile = blockIdx.x & 31;
  int k0r = (tile >> 2) * 64, n0 = (tile & 3) * 128;
  int lane = tid & 63, wave = tid >> 6, wm = wave >> 1, wn = wave & 1;
  int r_ = tid >> 3, kc = (tid & 7) * 8;
  floatx4 acc[2][4] = {};
  for (int term = 0; term < 2; ++term) {
    if (term == 0 && j > m) continue;
    if (term == 1 && j < 1) continue;
    const float* Psrc = Pin + (size_t)(term == 0 ? j : j - 1) * 262144;
    const int coloff = (term == 0) ? 512 : 0;   // term0: W2, term1: W1
    for (int v = 0; v < 3; ++v) {                // (hi,hi),(hi,lo),(lo,hi)
      int va = (v == 2) ? 1 : 0;
      int vb = (v == 1) ? 1 : 0;
      for (int t0 = 0; t0 < 512; t0 += 64) {
#pragma unroll
        for (int p = 0; p < 2; ++p) {
          int row = r_ + p * 32;
          *(uint4*)&As[row * LDA + kc] = cvt8(Psrc + (size_t)(k0r + row) * 512 + t0 + kc, va);
        }
#pragma unroll
        for (int p = 0; p < 4; ++p) {
          int row = r_ + p * 32;
          *(uint4*)&Bs[row * LDA + kc] = cvt8(Ws + (size_t)(n0 + row) * 1024 + coloff + t0 + kc, vb);
        }
        __syncthreads();
        gemm_core24(As, Bs, acc, wm, wn, lane);
        __syncthreads();
      }
    }
  }
  int rb = lane & 15, rg = (lane >> 4) * 4;
#pragma unroll
  for (int i = 0; i < 2; ++i)
#pragma unroll
    for (int jj = 0; jj < 4; ++jj) {
      int col = n0 + wn * 64 + jj * 16 + rb;
#pragma unroll
      for (int reg = 0; reg < 4; ++reg) {
        int row = wm * 32 + i * 16 + rg + reg;
        Pout[(size_t)j * 262144 + (size_t)(k0r + row) * 512 + col] = acc[i][jj][reg];
      }
    }
}

// ---- P_1 = {W2^T, W1^T} f32 (transpose of W_sani halves) ----
__global__ __launch_bounds__(256) void k_trW(const float* __restrict__ Ws,
                                             float* __restrict__ P1) {
  __shared__ float t[64][65];
  int mat = blockIdx.x >> 6, tile = blockIdx.x & 63;
  int a0 = (tile >> 3) * 64, b0 = (tile & 7) * 64;
  int coloff = (mat == 0) ? 512 : 0;   // P_{1,0}=W2^T, P_{1,1}=W1^T
  for (int pp = 0; pp < 16; ++pp) {
    int idx = pp * 256 + threadIdx.x, rr = idx >> 6, cc = idx & 63;
    t[rr][cc] = Ws[(size_t)(b0 + rr) * 1024 + coloff + a0 + cc];
  }
  __syncthreads();
  for (int pp = 0; pp < 16; ++pp) {
    int idx = pp * 256 + threadIdx.x, rr = idx >> 6, cc = idx & 63;
    P1[(size_t)mat * 262144 + (size_t)(a0 + rr) * 512 + b0 + cc] = t[cc][rr];
  }
}

// ---- Bcat_r[i][q*512+t] = A_{r,r-q}[i][t] = P_{r,r-q}[t][i], f32 -> bf16 ----
__global__ __launch_bounds__(256) void k_trB(const float* __restrict__ Pr,
                                             unsigned short* __restrict__ Bout,
                                             int r) {
  __shared__ float t[64][65];
  int q = blockIdx.x >> 6, tile = blockIdx.x & 63;
  int t0 = (tile >> 3) * 64, i0 = (tile & 7) * 64;
  const float* P = Pr + (size_t)(r - q) * 262144;
  int ldB = (r + 1) * 512;
  for (int pp = 0; pp < 16; ++pp) {
    int idx = pp * 256 + threadIdx.x, rr = idx >> 6, cc = idx & 63;
    t[rr][cc] = P[(size_t)(t0 + rr) * 512 + i0 + cc];
  }
  __syncthreads();
  for (int pp = 0; pp < 16; ++pp) {
    int idx = pp * 256 + threadIdx.x, rr = idx >> 6, cc = idx & 63;
    Bout[(size_t)(i0 + rr) * ldB + q * 512 + t0 + cc] = f2b(t[cc][rr]);
  }
}

// ---- beta_{r+1}[i] = sum_k (W1+W2)[i][k] * beta_r[k] + b[i] ----
__global__ __launch_bounds__(64) void k_bias_step(const float* __restrict__ Ws,
                                                  const float* __restrict__ b,
                                                  const float* __restrict__ bprev,
                                                  float* __restrict__ bout) {
  int i = blockIdx.x, t = threadIdx.x;
  float p = 0.f;
  for (int k = t; k < 512; k += 64)
    p += (Ws[(size_t)i * 1024 + k] + Ws[(size_t)i * 1024 + 512 + k]) * bprev[k];
#pragma unroll
  for (int off = 32; off > 0; off >>= 1) p += __shfl_down(p, off, 64);
  if (t == 0) bout[i] = p + b[i];
}

// ---- phase 2: one multi-level step. BM=64, BN=64, 256 threads, 4 waves (2x2, 32x32/wave).
//      Double-buffered LDS, ONE barrier per K-step, depth-2 register prefetch (q0/q1).
//      main (r=m): h(s,L+m) for s in [L+m,63], K=(m+1)*512; diag r<m: outs[L+r].
//      Per-element MFMA K-order identical to prior rounds -> bit-identical numerics. ----
__global__ __launch_bounds__(256) void k_step(const unsigned short* __restrict__ src,
                                              unsigned short* __restrict__ dst,
                                              unsigned short* __restrict__ outs,
                                              const unsigned short* __restrict__ Bcat,
                                              const float* __restrict__ beta,
                                              int L_prev, int m, int nmain, int g) {
  __shared__ unsigned short As[2][64 * LDA];
  __shared__ unsigned short Bs[2][64 * LDA];
  const int tid = threadIdx.x, bid = blockIdx.x;
  const int mainWG = 128 * g;   // 8 xcd groups x g slabs x 16 (2 mhalf x 8 ntile)
  int r, s, sub;
  if (bid < mainWG) {
    int xcd = bid & 7, w = bid >> 3;
    int s_rel = xcd * g + (w >> 4);
    if (s_rel >= nmain) return;      // uniform exit, before any barrier
    sub = w & 15;
    r = m; s = L_prev + m + s_rel;
  } else {
    int db = bid - mainWG;
    r = 1 + (db >> 4); sub = db & 15;
    s = L_prev + r;
  }
  const int nb0 = (sub >> 3) * 64, n0 = (sub & 7) * 64;
  const int ldB = (r + 1) * 512;
  const unsigned short* Bp = Bcat + (size_t)262144 * (((r - 1) * (r + 2)) >> 1);
  const unsigned short* abase = src + (size_t)(s - r) * NH + (size_t)nb0 * HD;
  const float* bet = beta + (size_t)(r - 1) * 512;
  const int nk = (r + 1) * 8;        // always even (16,24,32,40)
  const int lane = tid & 63, wave = tid >> 6, wm = wave >> 1, wn = wave & 1;
  const int r_ = tid >> 3, kc = (tid & 7) * 8;

  floatx4 acc[2][2] = {};
  uint4 qa0[2], qb0[2], qa1[2], qb1[2];

#define LOADA(kcol, qa)                                                        \
  { int q_ = (kcol) >> 9, ac_ = (kcol) & 511;                                  \
    const unsigned short* a0_ = abase + (size_t)q_ * NH + ac_;                 \
    qa[0] = *(const uint4*)(a0_ + (size_t)r_ * HD + kc);                       \
    qa[1] = *(const uint4*)(a0_ + (size_t)(r_ + 32) * HD + kc); }
#define LOADB(kcol, qb)                                                        \
  { qb[0] = *(const uint4*)(Bp + (size_t)(n0 + r_) * ldB + (kcol) + kc);       \
    qb[1] = *(const uint4*)(Bp + (size_t)(n0 + r_ + 32) * ldB + (kcol) + kc); }
#define MFMA_PH(buf)                                                           \
  { const int rb_ = lane & 15, kg_ = (lane >> 4) * 8;                          \
    _Pragma("unroll")                                                          \
    for (int kk = 0; kk < 64; kk += 32) {                                      \
      short8 a_[2], b_[2];                                                     \
      _Pragma("unroll")                                                        \
      for (int i = 0; i < 2; ++i)                                              \
        a_[i] = *(const short8*)&As[buf][(wm * 32 + i * 16 + rb_) * LDA + kk + kg_]; \
      _Pragma("unroll")                                                        \
      for (int j = 0; j < 2; ++j)                                              \
        b_[j] = *(const short8*)&Bs[buf][(wn * 32 + j * 16 + rb_) * LDA + kk + kg_]; \
      _Pragma("unroll")                                                        \
      for (int i = 0; i < 2; ++i)                                              \
        _Pragma("unroll")                                                      \
        for (int j = 0; j < 2; ++j)                                            \
          acc[i][j] = __builtin_amdgcn_mfma_f32_16x16x32_bf16(a_[i], b_[j], acc[i][j], 0, 0, 0); \
    } }

  LOADA(0, qa0) LOADB(0, qb0)
  LOADA(64, qa1) LOADB(64, qb1)

  for (int k = 0; k < nk; k += 2) {
    // even step k -> buffer 0
    *(uint4*)&As[0][r_ * LDA + kc] = qa0[0];
    *(uint4*)&As[0][(r_ + 32) * LDA + kc] = qa0[1];
    *(uint4*)&Bs[0][r_ * LDA + kc] = qb0[0];
    *(uint4*)&Bs[0][(r_ + 32) * LDA + kc] = qb0[1];
    __syncthreads();
    if (k + 2 < nk) { LOADA((k + 2) * 64, qa0) LOADB((k + 2) * 64, qb0) }
    MFMA_PH(0)
    // odd step k+1 -> buffer 1
    *(uint4*)&As[1][r_ * LDA + kc] = qa1[0];
    *(uint4*)&As[1][(r_ + 32) * LDA + kc] = qa1[1];
    *(uint4*)&Bs[1][r_ * LDA + kc] = qb1[0];
    *(uint4*)&Bs[1][(r_ + 32) * LDA + kc] = qb1[1];
    __syncthreads();
    if (k + 3 < nk) { LOADA((k + 3) * 64, qa1) LOADB((k + 3) * 64, qb1) }
    MFMA_PH(1)
  }
#undef LOADA
#undef LOADB
#undef MFMA_PH

  const bool wdst = (r == m);
  const bool wout = (r < m) || (s == L_prev + m);   // outs[li] = h(li,li)
  unsigned short* d1 = dst + (size_t)s * NH + (size_t)nb0 * HD;
  unsigned short* d2 = outs + (size_t)s * NH + (size_t)nb0 * HD;
  const int rbc = lane & 15, rg = (lane >> 4) * 4;
#pragma unroll
  for (int i = 0; i < 2; ++i)
#pragma unroll
    for (int j = 0; j < 2; ++j) {
      int col = n0 + wn * 32 + j * 16 + rbc;
      float bv = bet[col];
#pragma unroll
      for (int reg = 0; reg < 4; ++reg) {
        int row = wm * 32 + i * 16 + rg + reg;
        unsigned short v = f2b(acc[i][j][reg] + bv);
        if (wdst) d1[(size_t)row * HD + col] = v;
        if (wout) d2[(size_t)row * HD + col] = v;
      }
    }
}

// ---- phase 3: Y = outs_flat @ W_out^T + b_out  (fp32 out) ----
__global__ __launch_bounds__(256) void k_gemm_out(const unsigned short* __restrict__ outs,
                                                  const unsigned short* __restrict__ Wb,
                                                  const float* __restrict__ bias,
                                                  float* __restrict__ Y) {
  __shared__ unsigned short As[64 * LDA];
  __shared__ unsigned short Bs[128 * LDA];
  int tid = threadIdx.x;
  int mtile = blockIdx.x >> 2, ntile = blockIdx.x & 3;
  int m0 = mtile * 64, n0 = ntile * 128;
  int lane = tid & 63, wave = tid >> 6, wm = wave >> 1, wn = wave & 1;
  floatx4 acc[2][4] = {};
  for (int k0 = 0; k0 < 512; k0 += 64) {
    stageA_bf16(As, outs + (size_t)m0 * 512 + k0, tid);
    stageB(Bs, Wb + (size_t)n0 * 512 + k0, 512, tid);
    __syncthreads();
    gemm_core24(As, Bs, acc, wm, wn, lane);
    __syncthreads();
  }
  int rb = lane & 15, rg = (lane >> 4) * 4;
#pragma unroll
  for (int i = 0; i < 2; ++i)
#pragma unroll
    for (int j = 0; j < 4; ++j) {
      int col = n0 + wn * 64 + j * 16 + rb;
      float bv = bias[col];
#pragma unroll
      for (int reg = 0; reg < 4; ++reg) {
        int row = m0 + wm * 32 + i * 16 + rg + reg;
        Y[(size_t)row * 512 + col] = acc[i][j][reg] + bv;
      }
    }
}

// ---- weights fp32 -> bf16: W_in -> Win_b, W_sani -> Bcat_1 (layout [W1|W2] as-is), W_out -> Wout_b ----
__global__ __launch_bounds__(256) void k_cvtw(const float* __restrict__ Win,
                                              const float* __restrict__ Wsani,
                                              const float* __restrict__ Wout,
                                              unsigned short* __restrict__ dWin,
                                              unsigned short* __restrict__ dBcat1,
                                              unsigned short* __restrict__ dWout) {
  int i = blockIdx.x * 256 + threadIdx.x;  // float4 index, total 262144
  const float* src;
  unsigned short* dst;
  int off;
  if (i < 65536)       { src = Win;   dst = dWin;   off = i; }
  else if (i < 196608) { src = Wsani; dst = dBcat1; off = i - 65536; }
  else                 { src = Wout;  dst = dWout;  off = i - 196608; }
  floatx4 v = *(const floatx4*)(src + (size_t)off * 4);
  uint2 u;
  u.x = (unsigned)f2b(v.x) | ((unsigned)f2b(v.y) << 16);
  u.y = (unsigned)f2b(v.z) | ((unsigned)f2b(v.w) << 16);
  *(uint2*)(dst + (size_t)off * 4) = u;
}

__global__ void k_copy(const uint4* __restrict__ src, uint4* __restrict__ dst, int n) {
  int i = blockIdx.x * blockDim.x + threadIdx.x;
  if (i < n) dst[i] = src[i];
}

// ---- loss: per n, column-softmax over 64 consecutive Y rows, dot with emb ----
__global__ __launch_bounds__(256) void k_loss(const float* __restrict__ Y,
                                              const float* __restrict__ table,
                                              const int* __restrict__ labels,
                                              float* __restrict__ partials) {
  int n = blockIdx.x, tid = threadIdx.x;
  float total = 0.f;
#pragma unroll
  for (int e2 = 0; e2 < 2; ++e2) {
    int e = e2 * 256 + tid;
    float mx = -1e30f;
    for (int l = 0; l < 64; ++l)
      mx = fmaxf(mx, Y[(size_t)(n * 64 + l) * 512 + e]);
    float se = 0.f;
    for (int l = 0; l < 64; ++l)
      se += expf(Y[(size_t)(n * 64 + l) * 512 + e] - mx);
    float lse = mx + logf(se);
    for (int l = 0; l < 64; ++l) {
      float embv = table[(size_t)labels[n * 64 + l] * ED + e];
      total += embv * (Y[(size_t)(n * 64 + l) * 512 + e] - lse);
    }
  }
  __shared__ float red[256];
  red[tid] = total;
  __syncthreads();
  for (int s2 = 128; s2 > 0; s2 >>= 1) {
    if (tid < s2) red[tid] += red[tid + s2];
    __syncthreads();
  }
  if (tid == 0) partials[n] = red[0];
}

__global__ void k_final(const float* __restrict__ partials, float* __restrict__ out) {
  if (threadIdx.x == 0) {
    double s = 0.0;
    for (int i = 0; i < 128; ++i) s += (double)partials[i];
    out[0] = (float)(-s / 65536.0);
  }
}

extern "C" void kernel_launch(void* const* d_in, const int* in_sizes, int n_in,
                              void* d_out, int out_size, void* d_ws, size_t ws_size,
                              hipStream_t stream) {
  const int*   labels = (const int*)d_in[0];
  const float* table  = (const float*)d_in[1];
  const float* W_in   = (const float*)d_in[2];
  const float* b_in   = (const float*)d_in[3];
  const float* W_sani = (const float*)d_in[4];
  const float* b_sani = (const float*)d_in[5];
  const float* W_out  = (const float*)d_in[6];
  const float* b_out  = (const float*)d_in[7];

  char* ws = (char*)d_ws;
  unsigned short* Win_b  = (unsigned short*)(ws + OFF_WIN);
  unsigned short* Wout_b = (unsigned short*)(ws + OFF_WOUT);
  unsigned short* xt     = (unsigned short*)(ws + OFF_XT);
  unsigned short* lvl0   = (unsigned short*)(ws + OFF_LVL0);
  unsigned short* lvl1   = (unsigned short*)(ws + OFF_LVL1);
  unsigned short* outs   = (unsigned short*)(ws + OFF_OUTS);
  float*          Pa     = (float*)(ws + OFF_PA);
  float*          Pb     = (float*)(ws + OFF_PB);
  unsigned short* Bcat   = (unsigned short*)(ws + OFF_BCAT);
  float*          beta   = (float*)(ws + OFF_BETA);
  float*          parts  = (float*)(ws + OFF_PART);
  float*          Y      = (float*)(ws + OFF_Y);

  // weights -> bf16 (Bcat_1 = bf16(W_sani) directly: layout [W1|W2] matches segment order)
  k_cvtw<<<1024, 256, 0, stream>>>(W_in, W_sani, W_out, Win_b, Bcat, Wout_b);
  k_gemm_emb<<<512, 256, 0, stream>>>(table, labels, Win_b, b_in, xt);
  k_copy<<<32, 256, 0, stream>>>((const uint4*)xt, (uint4*)outs, 8192);   // outs[0] = x_t[0]

  // bias chain beta_1..beta_4
  k_copy<<<1, 128, 0, stream>>>((const uint4*)b_sani, (uint4*)beta, 128);
  k_bias_step<<<512, 64, 0, stream>>>(W_sani, b_sani, beta,        beta + 512);
  k_bias_step<<<512, 64, 0, stream>>>(W_sani, b_sani, beta + 512,  beta + 1024);
  k_bias_step<<<512, 64, 0, stream>>>(W_sani, b_sani, beta + 1024, beta + 1536);

  // coefficient chain: P1 -> P2 -> P3 -> P4 (f32, hi/lo split GEMMs); Bcat_r via transpose
  k_trW <<<128, 256, 0, stream>>>(W_sani, Pa);                 // P1 (2 mats)
  k_coef<<< 96, 256, 0, stream>>>(Pa, Pb, W_sani, 1);          // P2 (3 mats)
  k_trB <<<192, 256, 0, stream>>>(Pb, Bcat + 524288, 2);
  k_coef<<<128, 256, 0, stream>>>(Pb, Pa, W_sani, 2);          // P3 (4 mats)
  k_trB <<<256, 256, 0, stream>>>(Pa, Bcat + 1310720, 3);
  k_coef<<<160, 256, 0, stream>>>(Pa, Pb, W_sani, 3);          // P4 (5 mats)
  k_trB <<<320, 256, 0, stream>>>(Pb, Bcat + 2359296, 4);

  // 16 multi-level steps (15 x m=4, 1 x m=3)
  const unsigned short* srcp = xt;
  for (int j = 1; j <= 16; ++j) {
    int L_prev = 4 * (j - 1);
    int m = (j == 16) ? 3 : 4;
    int nmain = 64 - (L_prev + m);
    int g = (nmain + 7) >> 3;
    unsigned short* dstp = ((j - 1) & 1) ? lvl1 : lvl0;
    k_step<<<128 * g + (m - 1) * 16, 256, 0, stream>>>(srcp, dstp, outs, Bcat, beta,
                                                       L_prev, m, nmain, g);
    srcp = dstp;
  }

  k_gemm_out<<<512, 256, 0, stream>>>(outs, Wout_b, b_out, Y);
  k_loss<<<128, 256, 0, stream>>>(Y, table, labels, parts);
  k_final<<<1, 64, 0, stream>>>(parts, (float*)d_out);
}

// Round 7
// 1694.446 us; speedup vs baseline: 1.3338x; 1.3338x over previous
//
#include <hip/hip_runtime.h>
#include <hip/hip_bf16.h>

typedef __attribute__((ext_vector_type(8))) short short8;
typedef __attribute__((ext_vector_type(4))) float floatx4;

#define NB 128      // batch N
#define LS 64       // seq L
#define HD 512      // hidden H
#define ED 512      // embed E
#define NH 65536    // NB*HD elements per s-slab
#define LDA 72      // LDS tile stride (64 + 8 pad, keeps 16B alignment)
#define LDC 136     // LDS C-tile stride (128 + 8 pad)

// ws layout (byte offsets)
#define OFF_WIN    0ull          // W_in bf16   [512*512]
#define OFF_WOUT   524288ull     // W_out bf16  [512*512]
#define OFF_XT     1048576ull    // x_t bf16    [64][128][512]  (= level 0)
#define OFF_LVL0   9437184ull    // level ping  bf16 [64][128][512]
#define OFF_LVL1   17825792ull   // level pong  bf16 [64][128][512]
#define OFF_OUTS   26214400ull   // outs bf16   [64][128][512]
#define OFF_PA     34603008ull   // coef chain ping f32 (up to 5x 512x512)
#define OFF_PB     39845888ull   // coef chain pong f32
#define OFF_BCAT   45088768ull   // Bcat_1..4 bf16 concat (7 MB)
#define OFF_BETA   52428800ull   // beta_1..4 f32 [4][512]
#define OFF_PART   52436992ull   // partials f32 [128]
#define OFF_Y      OFF_LVL0      // Y f32 [8192][512] aliases lvl bufs after recurrence

static __device__ __forceinline__ unsigned short f2b(float f) {
  unsigned u = __float_as_uint(f);
  u += 0x7fffu + ((u >> 16) & 1u);   // round-to-nearest-even
  return (unsigned short)(u >> 16);
}
static __device__ __forceinline__ float b2f(unsigned short h) {
  return __uint_as_float(((unsigned)h) << 16);
}

// load 8 consecutive f32, produce bf16x8 packed; variant 0 = hi, 1 = lo residual
static __device__ __forceinline__ uint4 cvt8(const float* s, int variant) {
  floatx4 f0 = *(const floatx4*)s;
  floatx4 f1 = *(const floatx4*)(s + 4);
  float f[8] = {f0.x, f0.y, f0.z, f0.w, f1.x, f1.y, f1.z, f1.w};
  unsigned short b[8];
#pragma unroll
  for (int k = 0; k < 8; ++k) {
    unsigned short h = f2b(f[k]);
    b[k] = (variant == 0) ? h : f2b(f[k] - b2f(h));
  }
  uint4 u;
  u.x = b[0] | ((unsigned)b[1] << 16); u.y = b[2] | ((unsigned)b[3] << 16);
  u.z = b[4] | ((unsigned)b[5] << 16); u.w = b[6] | ((unsigned)b[7] << 16);
  return u;
}

// ---- shared GEMM core: BM=64, BN=128, BK=64, 256 threads (4 waves, 2x2) ----
__device__ __forceinline__ void gemm_core24(const unsigned short* As, const unsigned short* Bs,
                                            floatx4 acc[2][4], int wm, int wn, int lane) {
  const int rb = lane & 15;
  const int kg = (lane >> 4) * 8;
#pragma unroll
  for (int kk = 0; kk < 64; kk += 32) {
    short8 a[2], b[4];
#pragma unroll
    for (int i = 0; i < 2; ++i)
      a[i] = *(const short8*)&As[(wm * 32 + i * 16 + rb) * LDA + kk + kg];
#pragma unroll
    for (int j = 0; j < 4; ++j)
      b[j] = *(const short8*)&Bs[(wn * 64 + j * 16 + rb) * LDA + kk + kg];
#pragma unroll
    for (int i = 0; i < 2; ++i)
#pragma unroll
      for (int j = 0; j < 4; ++j)
        acc[i][j] = __builtin_amdgcn_mfma_f32_16x16x32_bf16(a[i], b[j], acc[i][j], 0, 0, 0);
  }
}

__device__ __forceinline__ void stageA_bf16(unsigned short* As, const unsigned short* src, int tid) {
  int r = tid >> 3, kc = (tid & 7) * 8;
#pragma unroll
  for (int p = 0; p < 2; ++p)
    *(uint4*)&As[(r + p * 32) * LDA + kc] = *(const uint4*)(src + (size_t)(r + p * 32) * 512 + kc);
}

__device__ __forceinline__ void stageA_emb(unsigned short* As, const float* table,
                                           const int* labels, int m0, int k0, int tid) {
  int r = tid >> 3, kc = (tid & 7) * 8;
#pragma unroll
  for (int p = 0; p < 2; ++p) {
    int row = r + p * 32;
    const float* s = table + (size_t)labels[m0 + row] * ED + k0 + kc;
    *(uint4*)&As[row * LDA + kc] = cvt8(s, 0);
  }
}

__device__ __forceinline__ void stageB(unsigned short* Bs, const unsigned short* src, int ldB, int tid) {
  int r = tid >> 3, kc = (tid & 7) * 8;
#pragma unroll
  for (int p = 0; p < 4; ++p)
    *(uint4*)&Bs[(r + p * 32) * LDA + kc] = *(const uint4*)(src + (size_t)(r + p * 32) * ldB + kc);
}

// ---- phase 1: x_t[l][n][h] = bf16( emb(labels) @ W_in^T + b_in ) ----
__global__ __launch_bounds__(256) void k_gemm_emb(const float* __restrict__ table,
                                                  const int* __restrict__ labels,
                                                  const unsigned short* __restrict__ Wb,
                                                  const float* __restrict__ bias,
                                                  unsigned short* __restrict__ xt) {
  __shared__ unsigned short As[64 * LDA];
  __shared__ unsigned short Bs[128 * LDA];
  int tid = threadIdx.x;
  int mtile = blockIdx.x >> 2, ntile = blockIdx.x & 3;
  int m0 = mtile * 64, n0 = ntile * 128;
  int lane = tid & 63, wave = tid >> 6, wm = wave >> 1, wn = wave & 1;
  floatx4 acc[2][4] = {};
  for (int k0 = 0; k0 < 512; k0 += 64) {
    stageA_emb(As, table, labels, m0, k0, tid);
    stageB(Bs, Wb + (size_t)n0 * 512 + k0, 512, tid);
    __syncthreads();
    gemm_core24(As, Bs, acc, wm, wn, lane);
    __syncthreads();
  }
  int rb = lane & 15, rg = (lane >> 4) * 4;
#pragma unroll
  for (int i = 0; i < 2; ++i)
#pragma unroll
    for (int j = 0; j < 4; ++j) {
      int col = n0 + wn * 64 + j * 16 + rb;
      float bv = bias[col];
#pragma unroll
      for (int reg = 0; reg < 4; ++reg) {
        int m = m0 + wm * 32 + i * 16 + rg + reg;
        int n = m >> 6, l = m & 63;
        xt[((size_t)l * NB + n) * HD + col] = f2b(acc[i][j][reg] + bv);
      }
    }
}

// ---- coefficient chain iteration: P_{m+1,j} = gemm(P_{m,j}, W2) + gemm(P_{m,j-1}, W1)
//      P stored transposed ([k][t] row-major, P = A^T). hi/lo split (3 terms) for ~f32 accuracy. ----
__global__ __launch_bounds__(256) void k_coef(const float* __restrict__ Pin,
                                              float* __restrict__ Pout,
                                              const float* __restrict__ Ws,
                                              int m) {
  __shared__ unsigned short As[64 * LDA];
  __shared__ unsigned short Bs[128 * LDA];
  int tid = threadIdx.x;
  int j = blockIdx.x >> 5, tile = blockIdx.x & 31;
  int k0r = (tile >> 2) * 64, n0 = (tile & 3) * 128;
  int lane = tid & 63, wave = tid >> 6, wm = wave >> 1, wn = wave & 1;
  int r_ = tid >> 3, kc = (tid & 7) * 8;
  floatx4 acc[2][4] = {};
  for (int term = 0; term < 2; ++term) {
    if (term == 0 && j > m) continue;
    if (term == 1 && j < 1) continue;
    const float* Psrc = Pin + (size_t)(term == 0 ? j : j - 1) * 262144;
    const int coloff = (term == 0) ? 512 : 0;   // term0: W2, term1: W1
    for (int v = 0; v < 3; ++v) {                // (hi,hi),(hi,lo),(lo,hi)
      int va = (v == 2) ? 1 : 0;
      int vb = (v == 1) ? 1 : 0;
      for (int t0 = 0; t0 < 512; t0 += 64) {
#pragma unroll
        for (int p = 0; p < 2; ++p) {
          int row = r_ + p * 32;
          *(uint4*)&As[row * LDA + kc] = cvt8(Psrc + (size_t)(k0r + row) * 512 + t0 + kc, va);
        }
#pragma unroll
        for (int p = 0; p < 4; ++p) {
          int row = r_ + p * 32;
          *(uint4*)&Bs[row * LDA + kc] = cvt8(Ws + (size_t)(n0 + row) * 1024 + coloff + t0 + kc, vb);
        }
        __syncthreads();
        gemm_core24(As, Bs, acc, wm, wn, lane);
        __syncthreads();
      }
    }
  }
  int rb = lane & 15, rg = (lane >> 4) * 4;
#pragma unroll
  for (int i = 0; i < 2; ++i)
#pragma unroll
    for (int jj = 0; jj < 4; ++jj) {
      int col = n0 + wn * 64 + jj * 16 + rb;
#pragma unroll
      for (int reg = 0; reg < 4; ++reg) {
        int row = wm * 32 + i * 16 + rg + reg;
        Pout[(size_t)j * 262144 + (size_t)(k0r + row) * 512 + col] = acc[i][jj][reg];
      }
    }
}

// ---- P_1 = {W2^T, W1^T} f32 (transpose of W_sani halves) ----
__global__ __launch_bounds__(256) void k_trW(const float* __restrict__ Ws,
                                             float* __restrict__ P1) {
  __shared__ float t[64][65];
  int mat = blockIdx.x >> 6, tile = blockIdx.x & 63;
  int a0 = (tile >> 3) * 64, b0 = (tile & 7) * 64;
  int coloff = (mat == 0) ? 512 : 0;   // P_{1,0}=W2^T, P_{1,1}=W1^T
  for (int pp = 0; pp < 16; ++pp) {
    int idx = pp * 256 + threadIdx.x, rr = idx >> 6, cc = idx & 63;
    t[rr][cc] = Ws[(size_t)(b0 + rr) * 1024 + coloff + a0 + cc];
  }
  __syncthreads();
  for (int pp = 0; pp < 16; ++pp) {
    int idx = pp * 256 + threadIdx.x, rr = idx >> 6, cc = idx & 63;
    P1[(size_t)mat * 262144 + (size_t)(a0 + rr) * 512 + b0 + cc] = t[cc][rr];
  }
}

// ---- Bcat_r[i][q*512+t] = A_{r,r-q}[i][t] = P_{r,r-q}[t][i], f32 -> bf16 ----
__global__ __launch_bounds__(256) void k_trB(const float* __restrict__ Pr,
                                             unsigned short* __restrict__ Bout,
                                             int r) {
  __shared__ float t[64][65];
  int q = blockIdx.x >> 6, tile = blockIdx.x & 63;
  int t0 = (tile >> 3) * 64, i0 = (tile & 7) * 64;
  const float* P = Pr + (size_t)(r - q) * 262144;
  int ldB = (r + 1) * 512;
  for (int pp = 0; pp < 16; ++pp) {
    int idx = pp * 256 + threadIdx.x, rr = idx >> 6, cc = idx & 63;
    t[rr][cc] = P[(size_t)(t0 + rr) * 512 + i0 + cc];
  }
  __syncthreads();
  for (int pp = 0; pp < 16; ++pp) {
    int idx = pp * 256 + threadIdx.x, rr = idx >> 6, cc = idx & 63;
    Bout[(size_t)(i0 + rr) * ldB + q * 512 + t0 + cc] = f2b(t[cc][rr]);
  }
}

// ---- beta_{r+1}[i] = sum_k (W1+W2)[i][k] * beta_r[k] + b[i] ----
__global__ __launch_bounds__(64) void k_bias_step(const float* __restrict__ Ws,
                                                  const float* __restrict__ b,
                                                  const float* __restrict__ bprev,
                                                  float* __restrict__ bout) {
  int i = blockIdx.x, t = threadIdx.x;
  float p = 0.f;
  for (int k = t; k < 512; k += 64)
    p += (Ws[(size_t)i * 1024 + k] + Ws[(size_t)i * 1024 + 512 + k]) * bprev[k];
#pragma unroll
  for (int off = 32; off > 0; off >>= 1) p += __shfl_down(p, off, 64);
  if (t == 0) bout[i] = p + b[i];
}

// ---- phase 2: one multi-level step. BM=64, BN=128, 256 threads (4 waves, 2x2).
//      Double-buffered LDS, one barrier per K-step, depth-2 register prefetch.
//      Epilogue: C tile staged in LDS, then FULL-LINE coalesced uint4 stores
//      (each 128B line written once, by one wave) -> kills write amplification.
//      main (r=m): h(s,L+m) for s in [L+m,63], K=(m+1)*512; diag r<m: outs[L+r].
//      Per-element MFMA K-order identical to prior rounds -> bit-identical numerics. ----
__global__ __launch_bounds__(256) void k_step(const unsigned short* __restrict__ src,
                                              unsigned short* __restrict__ dst,
                                              unsigned short* __restrict__ outs,
                                              const unsigned short* __restrict__ Bcat,
                                              const float* __restrict__ beta,
                                              int L_prev, int m, int nmain) {
  __shared__ unsigned short As[2][64 * LDA];    // 18.4 KB (also reused as C tile)
  __shared__ unsigned short Bs[2][128 * LDA];   // 36.9 KB
  const int tid = threadIdx.x, bid = blockIdx.x;
  const int mainWG = nmain * 8;
  int r, s;
  if (bid < mainWG) { r = m; s = L_prev + m + (bid >> 3); }
  else              { r = 1 + ((bid - mainWG) >> 3); s = L_prev + r; }
  const int sub = bid & 7, nb0 = (sub >> 2) * 64, n0 = (sub & 3) * 128;
  const int ldB = (r + 1) * 512;
  const unsigned short* Bp = Bcat + (size_t)262144 * (((r - 1) * (r + 2)) >> 1);
  const unsigned short* abase = src + (size_t)(s - r) * NH + (size_t)nb0 * HD;
  const float* bet = beta + (size_t)(r - 1) * 512;
  const int nk = (r + 1) * 8;        // always even (16,24,32,40)
  const int lane = tid & 63, wave = tid >> 6, wm = wave >> 1, wn = wave & 1;
  const int r_ = tid >> 3, kc = (tid & 7) * 8;

  floatx4 acc[2][4] = {};
  uint4 qa0[2], qb0[4], qa1[2], qb1[4];

#define LOADA(kcol, qa)                                                        \
  { int q_ = (kcol) >> 9, ac_ = (kcol) & 511;                                  \
    const unsigned short* a0_ = abase + (size_t)q_ * NH + ac_;                 \
    qa[0] = *(const uint4*)(a0_ + (size_t)r_ * HD + kc);                       \
    qa[1] = *(const uint4*)(a0_ + (size_t)(r_ + 32) * HD + kc); }
#define LOADB(kcol, qb)                                                        \
  { _Pragma("unroll")                                                          \
    for (int p = 0; p < 4; ++p)                                                \
      qb[p] = *(const uint4*)(Bp + (size_t)(n0 + r_ + p * 32) * ldB + (kcol) + kc); }
#define STORE_LDS(buf, qa, qb)                                                 \
  { *(uint4*)&As[buf][r_ * LDA + kc] = qa[0];                                  \
    *(uint4*)&As[buf][(r_ + 32) * LDA + kc] = qa[1];                           \
    _Pragma("unroll")                                                          \
    for (int p = 0; p < 4; ++p)                                                \
      *(uint4*)&Bs[buf][(r_ + p * 32) * LDA + kc] = qb[p]; }

  LOADA(0, qa0) LOADB(0, qb0)
  LOADA(64, qa1) LOADB(64, qb1)

  for (int k = 0; k < nk; k += 2) {
    STORE_LDS(0, qa0, qb0)
    __syncthreads();
    if (k + 2 < nk) { LOADA((k + 2) * 64, qa0) LOADB((k + 2) * 64, qb0) }
    gemm_core24(As[0], Bs[0], acc, wm, wn, lane);
    STORE_LDS(1, qa1, qb1)
    __syncthreads();
    if (k + 3 < nk) { LOADA((k + 3) * 64, qa1) LOADB((k + 3) * 64, qb1) }
    gemm_core24(As[1], Bs[1], acc, wm, wn, lane);
  }
#undef LOADA
#undef LOADB
#undef STORE_LDS

  // ---- epilogue: stage C (64x128 bf16) in LDS, then full-line stores ----
  __syncthreads();                       // all LDS reads done before reuse
  unsigned short* Ct = &As[0][0];        // 64 x LDC (= 17408 shorts <= 18432)
  const int rbc = lane & 15, rg = (lane >> 4) * 4;
#pragma unroll
  for (int i = 0; i < 2; ++i)
#pragma unroll
    for (int j = 0; j < 4; ++j) {
      int col = wn * 64 + j * 16 + rbc;            // 0..127 local
      float bv = bet[n0 + col];
#pragma unroll
      for (int reg = 0; reg < 4; ++reg) {
        int row = wm * 32 + i * 16 + rg + reg;     // 0..63 local
        Ct[row * LDC + col] = f2b(acc[i][j][reg] + bv);
      }
    }
  __syncthreads();
  const bool wdst = (r == m);
  const bool wout = (r < m) || (s == L_prev + m);  // outs[li] = h(li,li)
  unsigned short* d1 = dst  + (size_t)s * NH + (size_t)nb0 * HD + n0;
  unsigned short* d2 = outs + (size_t)s * NH + (size_t)nb0 * HD + n0;
  const int lrow = tid >> 4, lcol = (tid & 15) * 8;  // 16 thr x 16B = 256B/row
#pragma unroll
  for (int sweep = 0; sweep < 4; ++sweep) {
    int row = sweep * 16 + lrow;
    uint4 v = *(const uint4*)&Ct[row * LDC + lcol];
    if (wdst) *(uint4*)(d1 + (size_t)row * HD + lcol) = v;
    if (wout) *(uint4*)(d2 + (size_t)row * HD + lcol) = v;
  }
}

// ---- phase 3: Y = outs_flat @ W_out^T + b_out  (fp32 out) ----
__global__ __launch_bounds__(256) void k_gemm_out(const unsigned short* __restrict__ outs,
                                                  const unsigned short* __restrict__ Wb,
                                                  const float* __restrict__ bias,
                                                  float* __restrict__ Y) {
  __shared__ unsigned short As[64 * LDA];
  __shared__ unsigned short Bs[128 * LDA];
  int tid = threadIdx.x;
  int mtile = blockIdx.x >> 2, ntile = blockIdx.x & 3;
  int m0 = mtile * 64, n0 = ntile * 128;
  int lane = tid & 63, wave = tid >> 6, wm = wave >> 1, wn = wave & 1;
  floatx4 acc[2][4] = {};
  for (int k0 = 0; k0 < 512; k0 += 64) {
    stageA_bf16(As, outs + (size_t)m0 * 512 + k0, tid);
    stageB(Bs, Wb + (size_t)n0 * 512 + k0, 512, tid);
    __syncthreads();
    gemm_core24(As, Bs, acc, wm, wn, lane);
    __syncthreads();
  }
  int rb = lane & 15, rg = (lane >> 4) * 4;
#pragma unroll
  for (int i = 0; i < 2; ++i)
#pragma unroll
    for (int j = 0; j < 4; ++j) {
      int col = n0 + wn * 64 + j * 16 + rb;
      float bv = bias[col];
#pragma unroll
      for (int reg = 0; reg < 4; ++reg) {
        int row = m0 + wm * 32 + i * 16 + rg + reg;
        Y[(size_t)row * 512 + col] = acc[i][j][reg] + bv;
      }
    }
}

// ---- weights fp32 -> bf16: W_in -> Win_b, W_sani -> Bcat_1 (layout [W1|W2] as-is), W_out -> Wout_b ----
__global__ __launch_bounds__(256) void k_cvtw(const float* __restrict__ Win,
                                              const float* __restrict__ Wsani,
                                              const float* __restrict__ Wout,
                                              unsigned short* __restrict__ dWin,
                                              unsigned short* __restrict__ dBcat1,
                                              unsigned short* __restrict__ dWout) {
  int i = blockIdx.x * 256 + threadIdx.x;  // float4 index, total 262144
  const float* src;
  unsigned short* dst;
  int off;
  if (i < 65536)       { src = Win;   dst = dWin;   off = i; }
  else if (i < 196608) { src = Wsani; dst = dBcat1; off = i - 65536; }
  else                 { src = Wout;  dst = dWout;  off = i - 196608; }
  floatx4 v = *(const floatx4*)(src + (size_t)off * 4);
  uint2 u;
  u.x = (unsigned)f2b(v.x) | ((unsigned)f2b(v.y) << 16);
  u.y = (unsigned)f2b(v.z) | ((unsigned)f2b(v.w) << 16);
  *(uint2*)(dst + (size_t)off * 4) = u;
}

__global__ void k_copy(const uint4* __restrict__ src, uint4* __restrict__ dst, int n) {
  int i = blockIdx.x * blockDim.x + threadIdx.x;
  if (i < n) dst[i] = src[i];
}

// ---- loss: per n, column-softmax over 64 consecutive Y rows, dot with emb ----
__global__ __launch_bounds__(256) void k_loss(const float* __restrict__ Y,
                                              const float* __restrict__ table,
                                              const int* __restrict__ labels,
                                              float* __restrict__ partials) {
  int n = blockIdx.x, tid = threadIdx.x;
  float total = 0.f;
#pragma unroll
  for (int e2 = 0; e2 < 2; ++e2) {
    int e = e2 * 256 + tid;
    float mx = -1e30f;
    for (int l = 0; l < 64; ++l)
      mx = fmaxf(mx, Y[(size_t)(n * 64 + l) * 512 + e]);
    float se = 0.f;
    for (int l = 0; l < 64; ++l)
      se += expf(Y[(size_t)(n * 64 + l) * 512 + e] - mx);
    float lse = mx + logf(se);
    for (int l = 0; l < 64; ++l) {
      float embv = table[(size_t)labels[n * 64 + l] * ED + e];
      total += embv * (Y[(size_t)(n * 64 + l) * 512 + e] - lse);
    }
  }
  __shared__ float red[256];
  red[tid] = total;
  __syncthreads();
  for (int s2 = 128; s2 > 0; s2 >>= 1) {
    if (tid < s2) red[tid] += red[tid + s2];
    __syncthreads();
  }
  if (tid == 0) partials[n] = red[0];
}

__global__ void k_final(const float* __restrict__ partials, float* __restrict__ out) {
  if (threadIdx.x == 0) {
    double s = 0.0;
    for (int i = 0; i < 128; ++i) s += (double)partials[i];
    out[0] = (float)(-s / 65536.0);
  }
}

extern "C" void kernel_launch(void* const* d_in, const int* in_sizes, int n_in,
                              void* d_out, int out_size, void* d_ws, size_t ws_size,
                              hipStream_t stream) {
  const int*   labels = (const int*)d_in[0];
  const float* table  = (const float*)d_in[1];
  const float* W_in   = (const float*)d_in[2];
  const float* b_in   = (const float*)d_in[3];
  const float* W_sani = (const float*)d_in[4];
  const float* b_sani = (const float*)d_in[5];
  const float* W_out  = (const float*)d_in[6];
  const float* b_out  = (const float*)d_in[7];

  char* ws = (char*)d_ws;
  unsigned short* Win_b  = (unsigned short*)(ws + OFF_WIN);
  unsigned short* Wout_b = (unsigned short*)(ws + OFF_WOUT);
  unsigned short* xt     = (unsigned short*)(ws + OFF_XT);
  unsigned short* lvl0   = (unsigned short*)(ws + OFF_LVL0);
  unsigned short* lvl1   = (unsigned short*)(ws + OFF_LVL1);
  unsigned short* outs   = (unsigned short*)(ws + OFF_OUTS);
  float*          Pa     = (float*)(ws + OFF_PA);
  float*          Pb     = (float*)(ws + OFF_PB);
  unsigned short* Bcat   = (unsigned short*)(ws + OFF_BCAT);
  float*          beta   = (float*)(ws + OFF_BETA);
  float*          parts  = (float*)(ws + OFF_PART);
  float*          Y      = (float*)(ws + OFF_Y);

  // weights -> bf16 (Bcat_1 = bf16(W_sani) directly: layout [W1|W2] matches segment order)
  k_cvtw<<<1024, 256, 0, stream>>>(W_in, W_sani, W_out, Win_b, Bcat, Wout_b);
  k_gemm_emb<<<512, 256, 0, stream>>>(table, labels, Win_b, b_in, xt);
  k_copy<<<32, 256, 0, stream>>>((const uint4*)xt, (uint4*)outs, 8192);   // outs[0] = x_t[0]

  // bias chain beta_1..beta_4
  k_copy<<<1, 128, 0, stream>>>((const uint4*)b_sani, (uint4*)beta, 128);
  k_bias_step<<<512, 64, 0, stream>>>(W_sani, b_sani, beta,        beta + 512);
  k_bias_step<<<512, 64, 0, stream>>>(W_sani, b_sani, beta + 512,  beta + 1024);
  k_bias_step<<<512, 64, 0, stream>>>(W_sani, b_sani, beta + 1024, beta + 1536);

  // coefficient chain: P1 -> P2 -> P3 -> P4 (f32, hi/lo split GEMMs); Bcat_r via transpose
  k_trW <<<128, 256, 0, stream>>>(W_sani, Pa);                 // P1 (2 mats)
  k_coef<<< 96, 256, 0, stream>>>(Pa, Pb, W_sani, 1);          // P2 (3 mats)
  k_trB <<<192, 256, 0, stream>>>(Pb, Bcat + 524288, 2);
  k_coef<<<128, 256, 0, stream>>>(Pb, Pa, W_sani, 2);          // P3 (4 mats)
  k_trB <<<256, 256, 0, stream>>>(Pa, Bcat + 1310720, 3);
  k_coef<<<160, 256, 0, stream>>>(Pa, Pb, W_sani, 3);          // P4 (5 mats)
  k_trB <<<320, 256, 0, stream>>>(Pb, Bcat + 2359296, 4);

  // 16 multi-level steps (15 x m=4, 1 x m=3)
  const unsigned short* srcp = xt;
  for (int j = 1; j <= 16; ++j) {
    int L_prev = 4 * (j - 1);
    int m = (j == 16) ? 3 : 4;
    int nmain = 64 - (L_prev + m);
    unsigned short* dstp = ((j - 1) & 1) ? lvl1 : lvl0;
    k_step<<<(nmain + m - 1) * 8, 256, 0, stream>>>(srcp, dstp, outs, Bcat, beta,
                                                    L_prev, m, nmain);
    srcp = dstp;
  }

  k_gemm_out<<<512, 256, 0, stream>>>(outs, Wout_b, b_out, Y);
  k_loss<<<128, 256, 0, stream>>>(Y, table, labels, parts);
  k_final<<<1, 64, 0, stream>>>(parts, (float*)d_out);
}

// Round 8
// 1684.106 us; speedup vs baseline: 1.3420x; 1.0061x over previous
//
#include <hip/hip_runtime.h>
#include <hip/hip_bf16.h>

typedef __attribute__((ext_vector_type(8))) short short8;
typedef __attribute__((ext_vector_type(4))) float floatx4;

#define NB 128      // batch N
#define LS 64       // seq L
#define HD 512      // hidden H
#define ED 512      // embed E
#define NH 65536    // NB*HD elements per s-slab
#define LDA 72      // LDS tile stride (64 + 8 pad, keeps 16B alignment)
#define LDC 136     // LDS C-tile stride (128 + 8 pad)

// ws layout (byte offsets)
#define OFF_WIN    0ull          // W_in bf16   [512*512]
#define OFF_WOUT   524288ull     // W_out bf16  [512*512]
#define OFF_XT     1048576ull    // x_t bf16    [64][128][512]  (= level 0)
#define OFF_LVL0   9437184ull    // level ping  bf16 [64][128][512]
#define OFF_LVL1   17825792ull   // level pong  bf16 [64][128][512]
#define OFF_OUTS   26214400ull   // outs bf16   [64][128][512]
#define OFF_PA     34603008ull   // coef chain ping f32 (up to 5x 512x512)
#define OFF_PB     39845888ull   // coef chain pong f32
#define OFF_BCAT   45088768ull   // Bcat_1..4 bf16 concat (7 MB)
#define OFF_BETA   52428800ull   // beta_1..4 f32 [4][512]
#define OFF_PART   52436992ull   // partials f32 [128]
#define OFF_Y      OFF_LVL0      // Y f32 [8192][512] aliases lvl bufs after recurrence

static __device__ __forceinline__ unsigned short f2b(float f) {
  unsigned u = __float_as_uint(f);
  u += 0x7fffu + ((u >> 16) & 1u);   // round-to-nearest-even
  return (unsigned short)(u >> 16);
}
static __device__ __forceinline__ float b2f(unsigned short h) {
  return __uint_as_float(((unsigned)h) << 16);
}

// load 8 consecutive f32, produce bf16x8 packed; variant 0 = hi, 1 = lo residual
static __device__ __forceinline__ uint4 cvt8(const float* s, int variant) {
  floatx4 f0 = *(const floatx4*)s;
  floatx4 f1 = *(const floatx4*)(s + 4);
  float f[8] = {f0.x, f0.y, f0.z, f0.w, f1.x, f1.y, f1.z, f1.w};
  unsigned short b[8];
#pragma unroll
  for (int k = 0; k < 8; ++k) {
    unsigned short h = f2b(f[k]);
    b[k] = (variant == 0) ? h : f2b(f[k] - b2f(h));
  }
  uint4 u;
  u.x = b[0] | ((unsigned)b[1] << 16); u.y = b[2] | ((unsigned)b[3] << 16);
  u.z = b[4] | ((unsigned)b[5] << 16); u.w = b[6] | ((unsigned)b[7] << 16);
  return u;
}

// ---- shared GEMM core: BM=64, BN=128, BK=64, 256 threads (4 waves, 2x2) ----
__device__ __forceinline__ void gemm_core24(const unsigned short* As, const unsigned short* Bs,
                                            floatx4 acc[2][4], int wm, int wn, int lane) {
  const int rb = lane & 15;
  const int kg = (lane >> 4) * 8;
#pragma unroll
  for (int kk = 0; kk < 64; kk += 32) {
    short8 a[2], b[4];
#pragma unroll
    for (int i = 0; i < 2; ++i)
      a[i] = *(const short8*)&As[(wm * 32 + i * 16 + rb) * LDA + kk + kg];
#pragma unroll
    for (int j = 0; j < 4; ++j)
      b[j] = *(const short8*)&Bs[(wn * 64 + j * 16 + rb) * LDA + kk + kg];
#pragma unroll
    for (int i = 0; i < 2; ++i)
#pragma unroll
      for (int j = 0; j < 4; ++j)
        acc[i][j] = __builtin_amdgcn_mfma_f32_16x16x32_bf16(a[i], b[j], acc[i][j], 0, 0, 0);
  }
}

__device__ __forceinline__ void stageA_bf16(unsigned short* As, const unsigned short* src, int tid) {
  int r = tid >> 3, kc = (tid & 7) * 8;
#pragma unroll
  for (int p = 0; p < 2; ++p)
    *(uint4*)&As[(r + p * 32) * LDA + kc] = *(const uint4*)(src + (size_t)(r + p * 32) * 512 + kc);
}

__device__ __forceinline__ void stageA_emb(unsigned short* As, const float* table,
                                           const int* labels, int m0, int k0, int tid) {
  int r = tid >> 3, kc = (tid & 7) * 8;
#pragma unroll
  for (int p = 0; p < 2; ++p) {
    int row = r + p * 32;
    const float* s = table + (size_t)labels[m0 + row] * ED + k0 + kc;
    *(uint4*)&As[row * LDA + kc] = cvt8(s, 0);
  }
}

__device__ __forceinline__ void stageB(unsigned short* Bs, const unsigned short* src, int ldB, int tid) {
  int r = tid >> 3, kc = (tid & 7) * 8;
#pragma unroll
  for (int p = 0; p < 4; ++p)
    *(uint4*)&Bs[(r + p * 32) * LDA + kc] = *(const uint4*)(src + (size_t)(r + p * 32) * ldB + kc);
}

// ---- phase 1: x_t[l][n][h] = bf16( emb(labels) @ W_in^T + b_in ) ----
__global__ __launch_bounds__(256) void k_gemm_emb(const float* __restrict__ table,
                                                  const int* __restrict__ labels,
                                                  const unsigned short* __restrict__ Wb,
                                                  const float* __restrict__ bias,
                                                  unsigned short* __restrict__ xt) {
  __shared__ unsigned short As[64 * LDA];
  __shared__ unsigned short Bs[128 * LDA];
  int tid = threadIdx.x;
  int mtile = blockIdx.x >> 2, ntile = blockIdx.x & 3;
  int m0 = mtile * 64, n0 = ntile * 128;
  int lane = tid & 63, wave = tid >> 6, wm = wave >> 1, wn = wave & 1;
  floatx4 acc[2][4] = {};
  for (int k0 = 0; k0 < 512; k0 += 64) {
    stageA_emb(As, table, labels, m0, k0, tid);
    stageB(Bs, Wb + (size_t)n0 * 512 + k0, 512, tid);
    __syncthreads();
    gemm_core24(As, Bs, acc, wm, wn, lane);
    __syncthreads();
  }
  int rb = lane & 15, rg = (lane >> 4) * 4;
#pragma unroll
  for (int i = 0; i < 2; ++i)
#pragma unroll
    for (int j = 0; j < 4; ++j) {
      int col = n0 + wn * 64 + j * 16 + rb;
      float bv = bias[col];
#pragma unroll
      for (int reg = 0; reg < 4; ++reg) {
        int m = m0 + wm * 32 + i * 16 + rg + reg;
        int n = m >> 6, l = m & 63;
        xt[((size_t)l * NB + n) * HD + col] = f2b(acc[i][j][reg] + bv);
      }
    }
}

// ---- coefficient chain iteration: P_{m+1,j} = gemm(P_{m,j}, W2) + gemm(P_{m,j-1}, W1)
//      P stored transposed ([k][t] row-major, P = A^T). hi/lo split (3 terms) for ~f32 accuracy. ----
__global__ __launch_bounds__(256) void k_coef(const float* __restrict__ Pin,
                                              float* __restrict__ Pout,
                                              const float* __restrict__ Ws,
                                              int m) {
  __shared__ unsigned short As[64 * LDA];
  __shared__ unsigned short Bs[128 * LDA];
  int tid = threadIdx.x;
  int j = blockIdx.x >> 5, tile = blockIdx.x & 31;
  int k0r = (tile >> 2) * 64, n0 = (tile & 3) * 128;
  int lane = tid & 63, wave = tid >> 6, wm = wave >> 1, wn = wave & 1;
  int r_ = tid >> 3, kc = (tid & 7) * 8;
  floatx4 acc[2][4] = {};
  for (int term = 0; term < 2; ++term) {
    if (term == 0 && j > m) continue;
    if (term == 1 && j < 1) continue;
    const float* Psrc = Pin + (size_t)(term == 0 ? j : j - 1) * 262144;
    const int coloff = (term == 0) ? 512 : 0;   // term0: W2, term1: W1
    for (int v = 0; v < 3; ++v) {                // (hi,hi),(hi,lo),(lo,hi)
      int va = (v == 2) ? 1 : 0;
      int vb = (v == 1) ? 1 : 0;
      for (int t0 = 0; t0 < 512; t0 += 64) {
#pragma unroll
        for (int p = 0; p < 2; ++p) {
          int row = r_ + p * 32;
          *(uint4*)&As[row * LDA + kc] = cvt8(Psrc + (size_t)(k0r + row) * 512 + t0 + kc, va);
        }
#pragma unroll
        for (int p = 0; p < 4; ++p) {
          int row = r_ + p * 32;
          *(uint4*)&Bs[row * LDA + kc] = cvt8(Ws + (size_t)(n0 + row) * 1024 + coloff + t0 + kc, vb);
        }
        __syncthreads();
        gemm_core24(As, Bs, acc, wm, wn, lane);
        __syncthreads();
      }
    }
  }
  int rb = lane & 15, rg = (lane >> 4) * 4;
#pragma unroll
  for (int i = 0; i < 2; ++i)
#pragma unroll
    for (int jj = 0; jj < 4; ++jj) {
      int col = n0 + wn * 64 + jj * 16 + rb;
#pragma unroll
      for (int reg = 0; reg < 4; ++reg) {
        int row = wm * 32 + i * 16 + rg + reg;
        Pout[(size_t)j * 262144 + (size_t)(k0r + row) * 512 + col] = acc[i][jj][reg];
      }
    }
}

// ---- P_1 = {W2^T, W1^T} f32 (transpose of W_sani halves) ----
__global__ __launch_bounds__(256) void k_trW(const float* __restrict__ Ws,
                                             float* __restrict__ P1) {
  __shared__ float t[64][65];
  int mat = blockIdx.x >> 6, tile = blockIdx.x & 63;
  int a0 = (tile >> 3) * 64, b0 = (tile & 7) * 64;
  int coloff = (mat == 0) ? 512 : 0;   // P_{1,0}=W2^T, P_{1,1}=W1^T
  for (int pp = 0; pp < 16; ++pp) {
    int idx = pp * 256 + threadIdx.x, rr = idx >> 6, cc = idx & 63;
    t[rr][cc] = Ws[(size_t)(b0 + rr) * 1024 + coloff + a0 + cc];
  }
  __syncthreads();
  for (int pp = 0; pp < 16; ++pp) {
    int idx = pp * 256 + threadIdx.x, rr = idx >> 6, cc = idx & 63;
    P1[(size_t)mat * 262144 + (size_t)(a0 + rr) * 512 + b0 + cc] = t[cc][rr];
  }
}

// ---- Bcat_r[i][q*512+t] = A_{r,r-q}[i][t] = P_{r,r-q}[t][i], f32 -> bf16 ----
__global__ __launch_bounds__(256) void k_trB(const float* __restrict__ Pr,
                                             unsigned short* __restrict__ Bout,
                                             int r) {
  __shared__ float t[64][65];
  int q = blockIdx.x >> 6, tile = blockIdx.x & 63;
  int t0 = (tile >> 3) * 64, i0 = (tile & 7) * 64;
  const float* P = Pr + (size_t)(r - q) * 262144;
  int ldB = (r + 1) * 512;
  for (int pp = 0; pp < 16; ++pp) {
    int idx = pp * 256 + threadIdx.x, rr = idx >> 6, cc = idx & 63;
    t[rr][cc] = P[(size_t)(t0 + rr) * 512 + i0 + cc];
  }
  __syncthreads();
  for (int pp = 0; pp < 16; ++pp) {
    int idx = pp * 256 + threadIdx.x, rr = idx >> 6, cc = idx & 63;
    Bout[(size_t)(i0 + rr) * ldB + q * 512 + t0 + cc] = f2b(t[cc][rr]);
  }
}

// ---- beta_{r+1}[i] = sum_k (W1+W2)[i][k] * beta_r[k] + b[i] ----
__global__ __launch_bounds__(64) void k_bias_step(const float* __restrict__ Ws,
                                                  const float* __restrict__ b,
                                                  const float* __restrict__ bprev,
                                                  float* __restrict__ bout) {
  int i = blockIdx.x, t = threadIdx.x;
  float p = 0.f;
  for (int k = t; k < 512; k += 64)
    p += (Ws[(size_t)i * 1024 + k] + Ws[(size_t)i * 1024 + 512 + k]) * bprev[k];
#pragma unroll
  for (int off = 32; off > 0; off >>= 1) p += __shfl_down(p, off, 64);
  if (t == 0) bout[i] = p + b[i];
}

// ---- phase 2: one multi-level step. BM=64, BN=128, 256 threads (4 waves, 2x2).
//      Double-buffered LDS, one barrier per K-step, depth-2 register prefetch.
//      XCD-AFFINITY mapping: 8 XCDs = 4 s-groups x 2 n-groups; each XCD's
//      working set (2 B-panels 1.3MB + ~g+4 A-slabs 2.4MB) fits its 4MB L2.
//      Epilogue: LDS-staged C tile, full-line coalesced stores.
//      Per-element MFMA K-order identical to prior rounds -> bit-identical numerics. ----
__global__ __launch_bounds__(256) void k_step(const unsigned short* __restrict__ src,
                                              unsigned short* __restrict__ dst,
                                              unsigned short* __restrict__ outs,
                                              const unsigned short* __restrict__ Bcat,
                                              const float* __restrict__ beta,
                                              int L_prev, int m, int nmain, int g) {
  __shared__ unsigned short As[2][64 * LDA];    // 18.4 KB (reused as C tile)
  __shared__ unsigned short Bs[2][128 * LDA];   // 36.9 KB
  const int tid = threadIdx.x, bid = blockIdx.x;
  const int mainWG = 32 * g;   // 8 XCDs x g slabs x 4 (2 nb0 x 2 n-panels)
  int r, s, nb0, n0;
  if (bid < mainWG) {
    const int xcd = bid & 7, w = bid >> 3;        // dispatch round-robin -> XCD
    const int sgrp = xcd >> 1, ngrp = xcd & 1;
    const int s_rel = sgrp * g + (w >> 2);
    if (s_rel >= nmain) return;                    // uniform block exit (pre-barrier)
    const int sub2 = w & 3;
    nb0 = (sub2 >> 1) * 64;
    n0 = (ngrp * 2 + (sub2 & 1)) * 128;
    r = m; s = L_prev + m + s_rel;
  } else {
    const int db = bid - mainWG;
    r = 1 + (db >> 3);
    const int sub = db & 7;
    nb0 = (sub >> 2) * 64; n0 = (sub & 3) * 128;
    s = L_prev + r;
  }
  const int ldB = (r + 1) * 512;
  const unsigned short* Bp = Bcat + (size_t)262144 * (((r - 1) * (r + 2)) >> 1);
  const unsigned short* abase = src + (size_t)(s - r) * NH + (size_t)nb0 * HD;
  const float* bet = beta + (size_t)(r - 1) * 512;
  const int nk = (r + 1) * 8;        // always even (16,24,32,40)
  const int lane = tid & 63, wave = tid >> 6, wm = wave >> 1, wn = wave & 1;
  const int r_ = tid >> 3, kc = (tid & 7) * 8;

  floatx4 acc[2][4] = {};
  uint4 qa0[2], qb0[4], qa1[2], qb1[4];

#define LOADA(kcol, qa)                                                        \
  { int q_ = (kcol) >> 9, ac_ = (kcol) & 511;                                  \
    const unsigned short* a0_ = abase + (size_t)q_ * NH + ac_;                 \
    qa[0] = *(const uint4*)(a0_ + (size_t)r_ * HD + kc);                       \
    qa[1] = *(const uint4*)(a0_ + (size_t)(r_ + 32) * HD + kc); }
#define LOADB(kcol, qb)                                                        \
  { _Pragma("unroll")                                                          \
    for (int p = 0; p < 4; ++p)                                                \
      qb[p] = *(const uint4*)(Bp + (size_t)(n0 + r_ + p * 32) * ldB + (kcol) + kc); }
#define STORE_LDS(buf, qa, qb)                                                 \
  { *(uint4*)&As[buf][r_ * LDA + kc] = qa[0];                                  \
    *(uint4*)&As[buf][(r_ + 32) * LDA + kc] = qa[1];                           \
    _Pragma("unroll")                                                          \
    for (int p = 0; p < 4; ++p)                                                \
      *(uint4*)&Bs[buf][(r_ + p * 32) * LDA + kc] = qb[p]; }

  LOADA(0, qa0) LOADB(0, qb0)
  LOADA(64, qa1) LOADB(64, qb1)

  for (int k = 0; k < nk; k += 2) {
    STORE_LDS(0, qa0, qb0)
    __syncthreads();
    if (k + 2 < nk) { LOADA((k + 2) * 64, qa0) LOADB((k + 2) * 64, qb0) }
    gemm_core24(As[0], Bs[0], acc, wm, wn, lane);
    STORE_LDS(1, qa1, qb1)
    __syncthreads();
    if (k + 3 < nk) { LOADA((k + 3) * 64, qa1) LOADB((k + 3) * 64, qb1) }
    gemm_core24(As[1], Bs[1], acc, wm, wn, lane);
  }
#undef LOADA
#undef LOADB
#undef STORE_LDS

  // ---- epilogue: stage C (64x128 bf16) in LDS, then full-line stores ----
  __syncthreads();                       // all LDS reads done before reuse
  unsigned short* Ct = &As[0][0];        // 64 x LDC (= 17408 shorts <= 18432)
  const int rbc = lane & 15, rg = (lane >> 4) * 4;
#pragma unroll
  for (int i = 0; i < 2; ++i)
#pragma unroll
    for (int j = 0; j < 4; ++j) {
      int col = wn * 64 + j * 16 + rbc;            // 0..127 local
      float bv = bet[n0 + col];
#pragma unroll
      for (int reg = 0; reg < 4; ++reg) {
        int row = wm * 32 + i * 16 + rg + reg;     // 0..63 local
        Ct[row * LDC + col] = f2b(acc[i][j][reg] + bv);
      }
    }
  __syncthreads();
  const bool wdst = (r == m);
  const bool wout = (r < m) || (s == L_prev + m);  // outs[li] = h(li,li)
  unsigned short* d1 = dst  + (size_t)s * NH + (size_t)nb0 * HD + n0;
  unsigned short* d2 = outs + (size_t)s * NH + (size_t)nb0 * HD + n0;
  const int lrow = tid >> 4, lcol = (tid & 15) * 8;  // 16 thr x 16B = 256B/row
#pragma unroll
  for (int sweep = 0; sweep < 4; ++sweep) {
    int row = sweep * 16 + lrow;
    uint4 v = *(const uint4*)&Ct[row * LDC + lcol];
    if (wdst) *(uint4*)(d1 + (size_t)row * HD + lcol) = v;
    if (wout) *(uint4*)(d2 + (size_t)row * HD + lcol) = v;
  }
}

// ---- phase 3: Y = outs_flat @ W_out^T + b_out  (fp32 out) ----
__global__ __launch_bounds__(256) void k_gemm_out(const unsigned short* __restrict__ outs,
                                                  const unsigned short* __restrict__ Wb,
                                                  const float* __restrict__ bias,
                                                  float* __restrict__ Y) {
  __shared__ unsigned short As[64 * LDA];
  __shared__ unsigned short Bs[128 * LDA];
  int tid = threadIdx.x;
  int mtile = blockIdx.x >> 2, ntile = blockIdx.x & 3;
  int m0 = mtile * 64, n0 = ntile * 128;
  int lane = tid & 63, wave = tid >> 6, wm = wave >> 1, wn = wave & 1;
  floatx4 acc[2][4] = {};
  for (int k0 = 0; k0 < 512; k0 += 64) {
    stageA_bf16(As, outs + (size_t)m0 * 512 + k0, tid);
    stageB(Bs, Wb + (size_t)n0 * 512 + k0, 512, tid);
    __syncthreads();
    gemm_core24(As, Bs, acc, wm, wn, lane);
    __syncthreads();
  }
  int rb = lane & 15, rg = (lane >> 4) * 4;
#pragma unroll
  for (int i = 0; i < 2; ++i)
#pragma unroll
    for (int j = 0; j < 4; ++j) {
      int col = n0 + wn * 64 + j * 16 + rb;
      float bv = bias[col];
#pragma unroll
      for (int reg = 0; reg < 4; ++reg) {
        int row = m0 + wm * 32 + i * 16 + rg + reg;
        Y[(size_t)row * 512 + col] = acc[i][j][reg] + bv;
      }
    }
}

// ---- weights fp32 -> bf16: W_in -> Win_b, W_sani -> Bcat_1 (layout [W1|W2] as-is), W_out -> Wout_b ----
__global__ __launch_bounds__(256) void k_cvtw(const float* __restrict__ Win,
                                              const float* __restrict__ Wsani,
                                              const float* __restrict__ Wout,
                                              unsigned short* __restrict__ dWin,
                                              unsigned short* __restrict__ dBcat1,
                                              unsigned short* __restrict__ dWout) {
  int i = blockIdx.x * 256 + threadIdx.x;  // float4 index, total 262144
  const float* src;
  unsigned short* dst;
  int off;
  if (i < 65536)       { src = Win;   dst = dWin;   off = i; }
  else if (i < 196608) { src = Wsani; dst = dBcat1; off = i - 65536; }
  else                 { src = Wout;  dst = dWout;  off = i - 196608; }
  floatx4 v = *(const floatx4*)(src + (size_t)off * 4);
  uint2 u;
  u.x = (unsigned)f2b(v.x) | ((unsigned)f2b(v.y) << 16);
  u.y = (unsigned)f2b(v.z) | ((unsigned)f2b(v.w) << 16);
  *(uint2*)(dst + (size_t)off * 4) = u;
}

__global__ void k_copy(const uint4* __restrict__ src, uint4* __restrict__ dst, int n) {
  int i = blockIdx.x * blockDim.x + threadIdx.x;
  if (i < n) dst[i] = src[i];
}

// ---- loss: per n, column-softmax over 64 consecutive Y rows, dot with emb ----
__global__ __launch_bounds__(256) void k_loss(const float* __restrict__ Y,
                                              const float* __restrict__ table,
                                              const int* __restrict__ labels,
                                              float* __restrict__ partials) {
  int n = blockIdx.x, tid = threadIdx.x;
  float total = 0.f;
#pragma unroll
  for (int e2 = 0; e2 < 2; ++e2) {
    int e = e2 * 256 + tid;
    float mx = -1e30f;
    for (int l = 0; l < 64; ++l)
      mx = fmaxf(mx, Y[(size_t)(n * 64 + l) * 512 + e]);
    float se = 0.f;
    for (int l = 0; l < 64; ++l)
      se += expf(Y[(size_t)(n * 64 + l) * 512 + e] - mx);
    float lse = mx + logf(se);
    for (int l = 0; l < 64; ++l) {
      float embv = table[(size_t)labels[n * 64 + l] * ED + e];
      total += embv * (Y[(size_t)(n * 64 + l) * 512 + e] - lse);
    }
  }
  __shared__ float red[256];
  red[tid] = total;
  __syncthreads();
  for (int s2 = 128; s2 > 0; s2 >>= 1) {
    if (tid < s2) red[tid] += red[tid + s2];
    __syncthreads();
  }
  if (tid == 0) partials[n] = red[0];
}

__global__ void k_final(const float* __restrict__ partials, float* __restrict__ out) {
  if (threadIdx.x == 0) {
    double s = 0.0;
    for (int i = 0; i < 128; ++i) s += (double)partials[i];
    out[0] = (float)(-s / 65536.0);
  }
}

extern "C" void kernel_launch(void* const* d_in, const int* in_sizes, int n_in,
                              void* d_out, int out_size, void* d_ws, size_t ws_size,
                              hipStream_t stream) {
  const int*   labels = (const int*)d_in[0];
  const float* table  = (const float*)d_in[1];
  const float* W_in   = (const float*)d_in[2];
  const float* b_in   = (const float*)d_in[3];
  const float* W_sani = (const float*)d_in[4];
  const float* b_sani = (const float*)d_in[5];
  const float* W_out  = (const float*)d_in[6];
  const float* b_out  = (const float*)d_in[7];

  char* ws = (char*)d_ws;
  unsigned short* Win_b  = (unsigned short*)(ws + OFF_WIN);
  unsigned short* Wout_b = (unsigned short*)(ws + OFF_WOUT);
  unsigned short* xt     = (unsigned short*)(ws + OFF_XT);
  unsigned short* lvl0   = (unsigned short*)(ws + OFF_LVL0);
  unsigned short* lvl1   = (unsigned short*)(ws + OFF_LVL1);
  unsigned short* outs   = (unsigned short*)(ws + OFF_OUTS);
  float*          Pa     = (float*)(ws + OFF_PA);
  float*          Pb     = (float*)(ws + OFF_PB);
  unsigned short* Bcat   = (unsigned short*)(ws + OFF_BCAT);
  float*          beta   = (float*)(ws + OFF_BETA);
  float*          parts  = (float*)(ws + OFF_PART);
  float*          Y      = (float*)(ws + OFF_Y);

  // weights -> bf16 (Bcat_1 = bf16(W_sani) directly: layout [W1|W2] matches segment order)
  k_cvtw<<<1024, 256, 0, stream>>>(W_in, W_sani, W_out, Win_b, Bcat, Wout_b);
  k_gemm_emb<<<512, 256, 0, stream>>>(table, labels, Win_b, b_in, xt);
  k_copy<<<32, 256, 0, stream>>>((const uint4*)xt, (uint4*)outs, 8192);   // outs[0] = x_t[0]

  // bias chain beta_1..beta_4
  k_copy<<<1, 128, 0, stream>>>((const uint4*)b_sani, (uint4*)beta, 128);
  k_bias_step<<<512, 64, 0, stream>>>(W_sani, b_sani, beta,        beta + 512);
  k_bias_step<<<512, 64, 0, stream>>>(W_sani, b_sani, beta + 512,  beta + 1024);
  k_bias_step<<<512, 64, 0, stream>>>(W_sani, b_sani, beta + 1024, beta + 1536);

  // coefficient chain: P1 -> P2 -> P3 -> P4 (f32, hi/lo split GEMMs); Bcat_r via transpose
  k_trW <<<128, 256, 0, stream>>>(W_sani, Pa);                 // P1 (2 mats)
  k_coef<<< 96, 256, 0, stream>>>(Pa, Pb, W_sani, 1);          // P2 (3 mats)
  k_trB <<<192, 256, 0, stream>>>(Pb, Bcat + 524288, 2);
  k_coef<<<128, 256, 0, stream>>>(Pb, Pa, W_sani, 2);          // P3 (4 mats)
  k_trB <<<256, 256, 0, stream>>>(Pa, Bcat + 1310720, 3);
  k_coef<<<160, 256, 0, stream>>>(Pa, Pb, W_sani, 3);          // P4 (5 mats)
  k_trB <<<320, 256, 0, stream>>>(Pb, Bcat + 2359296, 4);

  // 16 multi-level steps (15 x m=4, 1 x m=3)
  const unsigned short* srcp = xt;
  for (int j = 1; j <= 16; ++j) {
    int L_prev = 4 * (j - 1);
    int m = (j == 16) ? 3 : 4;
    int nmain = 64 - (L_prev + m);
    int g = (nmain + 3) >> 2;          // slabs per s-group (4 s-groups)
    unsigned short* dstp = ((j - 1) & 1) ? lvl1 : lvl0;
    k_step<<<32 * g + (m - 1) * 8, 256, 0, stream>>>(srcp, dstp, outs, Bcat, beta,
                                                     L_prev, m, nmain, g);
    srcp = dstp;
  }

  k_gemm_out<<<512, 256, 0, stream>>>(outs, Wout_b, b_out, Y);
  k_loss<<<128, 256, 0, stream>>>(Y, table, labels, parts);
  k_final<<<1, 64, 0, stream>>>(parts, (float*)d_out);
}

// Round 9
// 691.097 us; speedup vs baseline: 3.2702x; 2.4369x over previous
//
#include <hip/hip_runtime.h>
#include <hip/hip_bf16.h>

typedef __attribute__((ext_vector_type(8))) short short8;
typedef __attribute__((ext_vector_type(4))) float floatx4;

#define NB 128      // batch N
#define LS 64       // seq L
#define HD 512      // hidden H
#define ED 512      // embed E
#define NH 65536    // NB*HD elements per s-slab
#define LDA 72      // LDS tile stride for reg-staged kernels (64 + 8 pad)
#define LDC 136     // LDS C-tile stride (128 + 8 pad)

// ws layout (byte offsets)
#define OFF_WIN    0ull          // W_in bf16   [512*512]
#define OFF_WOUT   524288ull     // W_out bf16  [512*512]
#define OFF_XT     1048576ull    // x_t bf16    [64][128][512]  (= level 0)
#define OFF_LVL0   9437184ull    // level ping  bf16 [64][128][512]
#define OFF_LVL1   17825792ull   // level pong  bf16 [64][128][512]
#define OFF_OUTS   26214400ull   // outs bf16   [64][128][512]
#define OFF_PA     34603008ull   // coef chain ping f32 (up to 5x 512x512)
#define OFF_PB     39845888ull   // coef chain pong f32
#define OFF_BCAT   45088768ull   // Bcat_1..4 bf16 concat (7 MB)
#define OFF_BETA   52428800ull   // beta_1..4 f32 [4][512]
#define OFF_PART   52436992ull   // partials f32 [128]
#define OFF_WSHI   52437504ull   // W_sani hi bf16 [512*1024] (1 MB)
#define OFF_WSLO   53486080ull   // W_sani lo bf16 (1 MB)
#define OFF_PHI    54534656ull   // P stage hi bf16 (<=5 mats, 2.62 MB)
#define OFF_PLO    57156096ull   // P stage lo bf16 (2.62 MB)
#define OFF_Y      OFF_LVL0      // Y f32 [8192][512] aliases lvl bufs after recurrence

static __device__ __forceinline__ unsigned short f2b(float f) {
  unsigned u = __float_as_uint(f);
  u += 0x7fffu + ((u >> 16) & 1u);   // round-to-nearest-even
  return (unsigned short)(u >> 16);
}
static __device__ __forceinline__ float b2f(unsigned short h) {
  return __uint_as_float(((unsigned)h) << 16);
}

// async global -> LDS, 16B per lane; LDS dest = wave-uniform base + lane*16
static __device__ __forceinline__ void gl_lds16(const unsigned short* g, unsigned short* l) {
  __builtin_amdgcn_global_load_lds(
      (const __attribute__((address_space(1))) void*)g,
      (__attribute__((address_space(3))) void*)l, 16, 0, 0);
}

// load 8 consecutive f32, produce bf16x8 packed (hi only; used for emb gather)
static __device__ __forceinline__ uint4 cvt8hi(const float* s) {
  floatx4 f0 = *(const floatx4*)s;
  floatx4 f1 = *(const floatx4*)(s + 4);
  float f[8] = {f0.x, f0.y, f0.z, f0.w, f1.x, f1.y, f1.z, f1.w};
  unsigned short b[8];
#pragma unroll
  for (int k = 0; k < 8; ++k) b[k] = f2b(f[k]);
  uint4 u;
  u.x = b[0] | ((unsigned)b[1] << 16); u.y = b[2] | ((unsigned)b[3] << 16);
  u.z = b[4] | ((unsigned)b[5] << 16); u.w = b[6] | ((unsigned)b[7] << 16);
  return u;
}

// ---- shared GEMM core (padded LDA=72): BM=64, BN=128, 256 threads (4 waves, 2x2) ----
__device__ __forceinline__ void gemm_core24(const unsigned short* As, const unsigned short* Bs,
                                            floatx4 acc[2][4], int wm, int wn, int lane) {
  const int rb = lane & 15;
  const int kg = (lane >> 4) * 8;
#pragma unroll
  for (int kk = 0; kk < 64; kk += 32) {
    short8 a[2], b[4];
#pragma unroll
    for (int i = 0; i < 2; ++i)
      a[i] = *(const short8*)&As[(wm * 32 + i * 16 + rb) * LDA + kk + kg];
#pragma unroll
    for (int j = 0; j < 4; ++j)
      b[j] = *(const short8*)&Bs[(wn * 64 + j * 16 + rb) * LDA + kk + kg];
#pragma unroll
    for (int i = 0; i < 2; ++i)
#pragma unroll
      for (int j = 0; j < 4; ++j)
        acc[i][j] = __builtin_amdgcn_mfma_f32_16x16x32_bf16(a[i], b[j], acc[i][j], 0, 0, 0);
  }
}

// ---- same core but UNPADDED stride 64 (for gload_lds-staged k_step) ----
__device__ __forceinline__ void gemm_core64(const unsigned short* As, const unsigned short* Bs,
                                            floatx4 acc[2][4], int wm, int wn, int lane) {
  const int rb = lane & 15;
  const int kg = (lane >> 4) * 8;
#pragma unroll
  for (int kk = 0; kk < 64; kk += 32) {
    short8 a[2], b[4];
#pragma unroll
    for (int i = 0; i < 2; ++i)
      a[i] = *(const short8*)&As[(wm * 32 + i * 16 + rb) * 64 + kk + kg];
#pragma unroll
    for (int j = 0; j < 4; ++j)
      b[j] = *(const short8*)&Bs[(wn * 64 + j * 16 + rb) * 64 + kk + kg];
#pragma unroll
    for (int i = 0; i < 2; ++i)
#pragma unroll
      for (int j = 0; j < 4; ++j)
        acc[i][j] = __builtin_amdgcn_mfma_f32_16x16x32_bf16(a[i], b[j], acc[i][j], 0, 0, 0);
  }
}

__device__ __forceinline__ void stageA_bf16(unsigned short* As, const unsigned short* src, int tid) {
  int r = tid >> 3, kc = (tid & 7) * 8;
#pragma unroll
  for (int p = 0; p < 2; ++p)
    *(uint4*)&As[(r + p * 32) * LDA + kc] = *(const uint4*)(src + (size_t)(r + p * 32) * 512 + kc);
}

__device__ __forceinline__ void stageA_emb(unsigned short* As, const float* table,
                                           const int* labels, int m0, int k0, int tid) {
  int r = tid >> 3, kc = (tid & 7) * 8;
#pragma unroll
  for (int p = 0; p < 2; ++p) {
    int row = r + p * 32;
    const float* s = table + (size_t)labels[m0 + row] * ED + k0 + kc;
    *(uint4*)&As[row * LDA + kc] = cvt8hi(s);
  }
}

__device__ __forceinline__ void stageB(unsigned short* Bs, const unsigned short* src, int ldB, int tid) {
  int r = tid >> 3, kc = (tid & 7) * 8;
#pragma unroll
  for (int p = 0; p < 4; ++p)
    *(uint4*)&Bs[(r + p * 32) * LDA + kc] = *(const uint4*)(src + (size_t)(r + p * 32) * ldB + kc);
}

// ---- phase 1: x_t[l][n][h] = bf16( emb(labels) @ W_in^T + b_in ) ----
__global__ __launch_bounds__(256) void k_gemm_emb(const float* __restrict__ table,
                                                  const int* __restrict__ labels,
                                                  const unsigned short* __restrict__ Wb,
                                                  const float* __restrict__ bias,
                                                  unsigned short* __restrict__ xt) {
  __shared__ unsigned short As[64 * LDA];
  __shared__ unsigned short Bs[128 * LDA];
  int tid = threadIdx.x;
  int mtile = blockIdx.x >> 2, ntile = blockIdx.x & 3;
  int m0 = mtile * 64, n0 = ntile * 128;
  int lane = tid & 63, wave = tid >> 6, wm = wave >> 1, wn = wave & 1;
  floatx4 acc[2][4] = {};
  for (int k0 = 0; k0 < 512; k0 += 64) {
    stageA_emb(As, table, labels, m0, k0, tid);
    stageB(Bs, Wb + (size_t)n0 * 512 + k0, 512, tid);
    __syncthreads();
    gemm_core24(As, Bs, acc, wm, wn, lane);
    __syncthreads();
  }
  int rb = lane & 15, rg = (lane >> 4) * 4;
#pragma unroll
  for (int i = 0; i < 2; ++i)
#pragma unroll
    for (int j = 0; j < 4; ++j) {
      int col = n0 + wn * 64 + j * 16 + rb;
      float bv = bias[col];
#pragma unroll
      for (int reg = 0; reg < 4; ++reg) {
        int m = m0 + wm * 32 + i * 16 + rg + reg;
        int n = m >> 6, l = m & 63;
        xt[((size_t)l * NB + n) * HD + col] = f2b(acc[i][j][reg] + bv);
      }
    }
}

// ---- W_sani -> hi/lo bf16 split (same formula as the old inline cvt8) ----
__global__ __launch_bounds__(256) void k_cvtWs(const float* __restrict__ Ws,
                                               unsigned short* __restrict__ Hi,
                                               unsigned short* __restrict__ Lo) {
  int i = blockIdx.x * 256 + threadIdx.x;          // 8-float chunk, total 65536
  const float* s = Ws + (size_t)i * 8;
  unsigned short hb[8], lb[8];
#pragma unroll
  for (int k = 0; k < 8; ++k) {
    float f = s[k];
    unsigned short H = f2b(f);
    hb[k] = H; lb[k] = f2b(f - b2f(H));
  }
  uint4 h, l;
  h.x = hb[0] | ((unsigned)hb[1] << 16); h.y = hb[2] | ((unsigned)hb[3] << 16);
  h.z = hb[4] | ((unsigned)hb[5] << 16); h.w = hb[6] | ((unsigned)hb[7] << 16);
  l.x = lb[0] | ((unsigned)lb[1] << 16); l.y = lb[2] | ((unsigned)lb[3] << 16);
  l.z = lb[4] | ((unsigned)lb[5] << 16); l.w = lb[6] | ((unsigned)lb[7] << 16);
  *(uint4*)(Hi + (size_t)i * 8) = h;
  *(uint4*)(Lo + (size_t)i * 8) = l;
}

// ---- P stage f32 -> hi/lo bf16 ----
__global__ __launch_bounds__(256) void k_cvtP(const float* __restrict__ P,
                                              unsigned short* __restrict__ Hi,
                                              unsigned short* __restrict__ Lo, int n8) {
  int i = blockIdx.x * 256 + threadIdx.x;
  if (i >= n8) return;
  const float* s = P + (size_t)i * 8;
  unsigned short hb[8], lb[8];
#pragma unroll
  for (int k = 0; k < 8; ++k) {
    float f = s[k];
    unsigned short H = f2b(f);
    hb[k] = H; lb[k] = f2b(f - b2f(H));
  }
  uint4 h, l;
  h.x = hb[0] | ((unsigned)hb[1] << 16); h.y = hb[2] | ((unsigned)hb[3] << 16);
  h.z = hb[4] | ((unsigned)hb[5] << 16); h.w = hb[6] | ((unsigned)hb[7] << 16);
  l.x = lb[0] | ((unsigned)lb[1] << 16); l.y = lb[2] | ((unsigned)lb[3] << 16);
  l.z = lb[4] | ((unsigned)lb[5] << 16); l.w = lb[6] | ((unsigned)lb[7] << 16);
  *(uint4*)(Hi + (size_t)i * 8) = h;
  *(uint4*)(Lo + (size_t)i * 8) = l;
}

// ---- coefficient chain: P_{m+1,j} = gemm(P_{m,j}, W2) + gemm(P_{m,j-1}, W1),
//      pure-bf16 staged from precomputed hi/lo splits (bit-identical to old cvt8 path). ----
__global__ __launch_bounds__(256) void k_coef(const unsigned short* __restrict__ Phi,
                                              const unsigned short* __restrict__ Plo,
                                              float* __restrict__ Pout,
                                              const unsigned short* __restrict__ WsHi,
                                              const unsigned short* __restrict__ WsLo,
                                              int m) {
  __shared__ unsigned short As[64 * LDA];
  __shared__ unsigned short Bs[128 * LDA];
  int tid = threadIdx.x;
  int j = blockIdx.x >> 5, tile = blockIdx.x & 31;
  int k0r = (tile >> 2) * 64, n0 = (tile & 3) * 128;
  int lane = tid & 63, wave = tid >> 6, wm = wave >> 1, wn = wave & 1;
  floatx4 acc[2][4] = {};
  for (int term = 0; term < 2; ++term) {
    if (term == 0 && j > m) continue;
    if (term == 1 && j < 1) continue;
    const size_t pbase = (size_t)(term == 0 ? j : j - 1) * 262144;
    const int coloff = (term == 0) ? 512 : 0;   // term0: W2, term1: W1
    for (int v = 0; v < 3; ++v) {                // (hi,hi),(hi,lo),(lo,hi)
      const unsigned short* Asrc = (v == 2 ? Plo : Phi) + pbase;
      const unsigned short* Bsrc = (v == 1 ? WsLo : WsHi);
      for (int t0 = 0; t0 < 512; t0 += 64) {
        stageA_bf16(As, Asrc + (size_t)k0r * 512 + t0, tid);
        stageB(Bs, Bsrc + (size_t)n0 * 1024 + coloff + t0, 1024, tid);
        __syncthreads();
        gemm_core24(As, Bs, acc, wm, wn, lane);
        __syncthreads();
      }
    }
  }
  int rb = lane & 15, rg = (lane >> 4) * 4;
#pragma unroll
  for (int i = 0; i < 2; ++i)
#pragma unroll
    for (int jj = 0; jj < 4; ++jj) {
      int col = n0 + wn * 64 + jj * 16 + rb;
#pragma unroll
      for (int reg = 0; reg < 4; ++reg) {
        int row = wm * 32 + i * 16 + rg + reg;
        Pout[(size_t)j * 262144 + (size_t)(k0r + row) * 512 + col] = acc[i][jj][reg];
      }
    }
}

// ---- P_1 = {W2^T, W1^T} f32 (transpose of W_sani halves) ----
__global__ __launch_bounds__(256) void k_trW(const float* __restrict__ Ws,
                                             float* __restrict__ P1) {
  __shared__ float t[64][65];
  int mat = blockIdx.x >> 6, tile = blockIdx.x & 63;
  int a0 = (tile >> 3) * 64, b0 = (tile & 7) * 64;
  int coloff = (mat == 0) ? 512 : 0;   // P_{1,0}=W2^T, P_{1,1}=W1^T
  for (int pp = 0; pp < 16; ++pp) {
    int idx = pp * 256 + threadIdx.x, rr = idx >> 6, cc = idx & 63;
    t[rr][cc] = Ws[(size_t)(b0 + rr) * 1024 + coloff + a0 + cc];
  }
  __syncthreads();
  for (int pp = 0; pp < 16; ++pp) {
    int idx = pp * 256 + threadIdx.x, rr = idx >> 6, cc = idx & 63;
    P1[(size_t)mat * 262144 + (size_t)(a0 + rr) * 512 + b0 + cc] = t[cc][rr];
  }
}

// ---- Bcat_r[i][q*512+t] = A_{r,r-q}[i][t] = P_{r,r-q}[t][i], f32 -> bf16 ----
__global__ __launch_bounds__(256) void k_trB(const float* __restrict__ Pr,
                                             unsigned short* __restrict__ Bout,
                                             int r) {
  __shared__ float t[64][65];
  int q = blockIdx.x >> 6, tile = blockIdx.x & 63;
  int t0 = (tile >> 3) * 64, i0 = (tile & 7) * 64;
  const float* P = Pr + (size_t)(r - q) * 262144;
  int ldB = (r + 1) * 512;
  for (int pp = 0; pp < 16; ++pp) {
    int idx = pp * 256 + threadIdx.x, rr = idx >> 6, cc = idx & 63;
    t[rr][cc] = P[(size_t)(t0 + rr) * 512 + i0 + cc];
  }
  __syncthreads();
  for (int pp = 0; pp < 16; ++pp) {
    int idx = pp * 256 + threadIdx.x, rr = idx >> 6, cc = idx & 63;
    Bout[(size_t)(i0 + rr) * ldB + q * 512 + t0 + cc] = f2b(t[cc][rr]);
  }
}

// ---- beta_{r+1}[i] = sum_k (W1+W2)[i][k] * beta_r[k] + b[i] ----
__global__ __launch_bounds__(64) void k_bias_step(const float* __restrict__ Ws,
                                                  const float* __restrict__ b,
                                                  const float* __restrict__ bprev,
                                                  float* __restrict__ bout) {
  int i = blockIdx.x, t = threadIdx.x;
  float p = 0.f;
  for (int k = t; k < 512; k += 64)
    p += (Ws[(size_t)i * 1024 + k] + Ws[(size_t)i * 1024 + 512 + k]) * bprev[k];
#pragma unroll
  for (int off = 32; off > 0; off >>= 1) p += __shfl_down(p, off, 64);
  if (t == 0) bout[i] = p + b[i];
}

// ---- phase 2: one multi-level step. BM=64, BN=128, 256 threads (4 waves, 2x2).
//      Minimal 2-phase template: STAGE(next via global_load_lds w16) || MFMA(cur),
//      one __syncthreads per K-step (vmcnt drain). Unpadded linear LDS (gload req),
//      double-buffered, 48 KB -> 3 blocks/CU. XCD-affinity mapping + full-line epilogue.
//      Per-element MFMA K-order identical to prior rounds -> bit-identical numerics. ----
__global__ __launch_bounds__(256) void k_step(const unsigned short* __restrict__ src,
                                              unsigned short* __restrict__ dst,
                                              unsigned short* __restrict__ outs,
                                              const unsigned short* __restrict__ Bcat,
                                              const float* __restrict__ beta,
                                              int L_prev, int m, int nmain, int g) {
  __shared__ unsigned short lds[24576];   // A0[4096] A1[4096] B0[8192] B1[8192] = 48 KB
  unsigned short* const A0 = lds;
  unsigned short* const A1 = lds + 4096;
  unsigned short* const B0 = lds + 8192;
  unsigned short* const B1 = lds + 16384;
  const int tid = threadIdx.x, bid = blockIdx.x;
  const int mainWG = 32 * g;   // 8 XCDs x g slabs x 4 (2 nb0 x 2 n-panels)
  int r, s, nb0, n0;
  if (bid < mainWG) {
    const int xcd = bid & 7, w = bid >> 3;        // dispatch round-robin -> XCD
    const int sgrp = xcd >> 1, ngrp = xcd & 1;
    const int s_rel = sgrp * g + (w >> 2);
    if (s_rel >= nmain) return;                    // uniform block exit (pre-barrier)
    const int sub2 = w & 3;
    nb0 = (sub2 >> 1) * 64;
    n0 = (ngrp * 2 + (sub2 & 1)) * 128;
    r = m; s = L_prev + m + s_rel;
  } else {
    const int db = bid - mainWG;
    r = 1 + (db >> 3);
    const int sub = db & 7;
    nb0 = (sub >> 2) * 64; n0 = (sub & 3) * 128;
    s = L_prev + r;
  }
  const int ldB = (r + 1) * 512;
  const unsigned short* Bp = Bcat + (size_t)262144 * (((r - 1) * (r + 2)) >> 1);
  const unsigned short* abase = src + (size_t)(s - r) * NH + (size_t)nb0 * HD;
  const float* bet = beta + (size_t)(r - 1) * 512;
  const int nk = (r + 1) * 8;        // always even (16,24,32,40)
  const int lane = tid & 63, wave = tid >> 6, wm = wave >> 1, wn = wave & 1;
  const int rr_ = tid >> 3, kc = (tid & 7) * 8;

  floatx4 acc[2][4] = {};

  // STAGE: 6 global_load_lds calls fill A (8KB) + B (16KB) of one buffer.
  // LDS linear layout [row][64] shorts matches lane mapping: row=tid>>3 (+32p), chunk=tid&7.
#define STAGE(Ab, Bb, kcol)                                                          \
  { int q_ = (kcol) >> 9, ac_ = (kcol) & 511;                                        \
    const unsigned short* a0_ = abase + (size_t)q_ * NH + ac_;                       \
    unsigned short* lA = (Ab) + (tid >> 6) * 512;                                    \
    unsigned short* lB = (Bb) + (tid >> 6) * 512;                                    \
    gl_lds16(a0_ + (size_t)rr_ * HD + kc, lA);                                       \
    gl_lds16(a0_ + (size_t)(rr_ + 32) * HD + kc, lA + 2048);                         \
    gl_lds16(Bp + (size_t)(n0 + rr_) * ldB + (kcol) + kc, lB);                       \
    gl_lds16(Bp + (size_t)(n0 + rr_ + 32) * ldB + (kcol) + kc, lB + 2048);           \
    gl_lds16(Bp + (size_t)(n0 + rr_ + 64) * ldB + (kcol) + kc, lB + 4096);           \
    gl_lds16(Bp + (size_t)(n0 + rr_ + 96) * ldB + (kcol) + kc, lB + 6144); }

  STAGE(A0, B0, 0)
  __syncthreads();                     // drain prologue loads
  for (int k = 0; k < nk; k += 2) {
    if (k + 1 < nk) STAGE(A1, B1, (k + 1) * 64)   // prefetch hides under MFMA
    gemm_core64(A0, B0, acc, wm, wn, lane);
    __syncthreads();                               // drain prefetch + WAR-protect A0/B0
    if (k + 2 < nk) STAGE(A0, B0, (k + 2) * 64)
    gemm_core64(A1, B1, acc, wm, wn, lane);
    __syncthreads();
  }
#undef STAGE

  // ---- epilogue: stage C (64x128 bf16) in LDS, then full-line stores ----
  unsigned short* Ct = lds;            // 64 x LDC = 8704 shorts <= 24576
  const int rbc = lane & 15, rg = (lane >> 4) * 4;
#pragma unroll
  for (int i = 0; i < 2; ++i)
#pragma unroll
    for (int j = 0; j < 4; ++j) {
      int col = wn * 64 + j * 16 + rbc;            // 0..127 local
      float bv = bet[n0 + col];
#pragma unroll
      for (int reg = 0; reg < 4; ++reg) {
        int row = wm * 32 + i * 16 + rg + reg;     // 0..63 local
        Ct[row * LDC + col] = f2b(acc[i][j][reg] + bv);
      }
    }
  __syncthreads();
  const bool wdst = (r == m);
  const bool wout = (r < m) || (s == L_prev + m);  // outs[li] = h(li,li)
  unsigned short* d1 = dst  + (size_t)s * NH + (size_t)nb0 * HD + n0;
  unsigned short* d2 = outs + (size_t)s * NH + (size_t)nb0 * HD + n0;
  const int lrow = tid >> 4, lcol = (tid & 15) * 8;  // 16 thr x 16B = 256B/row
#pragma unroll
  for (int sweep = 0; sweep < 4; ++sweep) {
    int row = sweep * 16 + lrow;
    uint4 v = *(const uint4*)&Ct[row * LDC + lcol];
    if (wdst) *(uint4*)(d1 + (size_t)row * HD + lcol) = v;
    if (wout) *(uint4*)(d2 + (size_t)row * HD + lcol) = v;
  }
}

// ---- phase 3: Y = outs_flat @ W_out^T + b_out  (fp32 out) ----
__global__ __launch_bounds__(256) void k_gemm_out(const unsigned short* __restrict__ outs,
                                                  const unsigned short* __restrict__ Wb,
                                                  const float* __restrict__ bias,
                                                  float* __restrict__ Y) {
  __shared__ unsigned short As[64 * LDA];
  __shared__ unsigned short Bs[128 * LDA];
  int tid = threadIdx.x;
  int mtile = blockIdx.x >> 2, ntile = blockIdx.x & 3;
  int m0 = mtile * 64, n0 = ntile * 128;
  int lane = tid & 63, wave = tid >> 6, wm = wave >> 1, wn = wave & 1;
  floatx4 acc[2][4] = {};
  for (int k0 = 0; k0 < 512; k0 += 64) {
    stageA_bf16(As, outs + (size_t)m0 * 512 + k0, tid);
    stageB(Bs, Wb + (size_t)n0 * 512 + k0, 512, tid);
    __syncthreads();
    gemm_core24(As, Bs, acc, wm, wn, lane);
    __syncthreads();
  }
  int rb = lane & 15, rg = (lane >> 4) * 4;
#pragma unroll
  for (int i = 0; i < 2; ++i)
#pragma unroll
    for (int j = 0; j < 4; ++j) {
      int col = n0 + wn * 64 + j * 16 + rb;
      float bv = bias[col];
#pragma unroll
      for (int reg = 0; reg < 4; ++reg) {
        int row = m0 + wm * 32 + i * 16 + rg + reg;
        Y[(size_t)row * 512 + col] = acc[i][j][reg] + bv;
      }
    }
}

// ---- weights fp32 -> bf16: W_in, W_sani (-> Bcat_1), W_out ----
__global__ __launch_bounds__(256) void k_cvtw(const float* __restrict__ Win,
                                              const float* __restrict__ Wsani,
                                              const float* __restrict__ Wout,
                                              unsigned short* __restrict__ dWin,
                                              unsigned short* __restrict__ dBcat1,
                                              unsigned short* __restrict__ dWout) {
  int i = blockIdx.x * 256 + threadIdx.x;  // float4 index, total 262144
  const float* src;
  unsigned short* dst;
  int off;
  if (i < 65536)       { src = Win;   dst = dWin;   off = i; }
  else if (i < 196608) { src = Wsani; dst = dBcat1; off = i - 65536; }
  else                 { src = Wout;  dst = dWout;  off = i - 196608; }
  floatx4 v = *(const floatx4*)(src + (size_t)off * 4);
  uint2 u;
  u.x = (unsigned)f2b(v.x) | ((unsigned)f2b(v.y) << 16);
  u.y = (unsigned)f2b(v.z) | ((unsigned)f2b(v.w) << 16);
  *(uint2*)(dst + (size_t)off * 4) = u;
}

__global__ void k_copy(const uint4* __restrict__ src, uint4* __restrict__ dst, int n) {
  int i = blockIdx.x * blockDim.x + threadIdx.x;
  if (i < n) dst[i] = src[i];
}

// ---- loss: per n, column-softmax over 64 consecutive Y rows, dot with emb ----
__global__ __launch_bounds__(256) void k_loss(const float* __restrict__ Y,
                                              const float* __restrict__ table,
                                              const int* __restrict__ labels,
                                              float* __restrict__ partials) {
  int n = blockIdx.x, tid = threadIdx.x;
  float total = 0.f;
#pragma unroll
  for (int e2 = 0; e2 < 2; ++e2) {
    int e = e2 * 256 + tid;
    float mx = -1e30f;
    for (int l = 0; l < 64; ++l)
      mx = fmaxf(mx, Y[(size_t)(n * 64 + l) * 512 + e]);
    float se = 0.f;
    for (int l = 0; l < 64; ++l)
      se += expf(Y[(size_t)(n * 64 + l) * 512 + e] - mx);
    float lse = mx + logf(se);
    for (int l = 0; l < 64; ++l) {
      float embv = table[(size_t)labels[n * 64 + l] * ED + e];
      total += embv * (Y[(size_t)(n * 64 + l) * 512 + e] - lse);
    }
  }
  __shared__ float red[256];
  red[tid] = total;
  __syncthreads();
  for (int s2 = 128; s2 > 0; s2 >>= 1) {
    if (tid < s2) red[tid] += red[tid + s2];
    __syncthreads();
  }
  if (tid == 0) partials[n] = red[0];
}

__global__ void k_final(const float* __restrict__ partials, float* __restrict__ out) {
  if (threadIdx.x == 0) {
    double s = 0.0;
    for (int i = 0; i < 128; ++i) s += (double)partials[i];
    out[0] = (float)(-s / 65536.0);
  }
}

extern "C" void kernel_launch(void* const* d_in, const int* in_sizes, int n_in,
                              void* d_out, int out_size, void* d_ws, size_t ws_size,
                              hipStream_t stream) {
  const int*   labels = (const int*)d_in[0];
  const float* table  = (const float*)d_in[1];
  const float* W_in   = (const float*)d_in[2];
  const float* b_in   = (const float*)d_in[3];
  const float* W_sani = (const float*)d_in[4];
  const float* b_sani = (const float*)d_in[5];
  const float* W_out  = (const float*)d_in[6];
  const float* b_out  = (const float*)d_in[7];

  char* ws = (char*)d_ws;
  unsigned short* Win_b  = (unsigned short*)(ws + OFF_WIN);
  unsigned short* Wout_b = (unsigned short*)(ws + OFF_WOUT);
  unsigned short* xt     = (unsigned short*)(ws + OFF_XT);
  unsigned short* lvl0   = (unsigned short*)(ws + OFF_LVL0);
  unsigned short* lvl1   = (unsigned short*)(ws + OFF_LVL1);
  unsigned short* outs   = (unsigned short*)(ws + OFF_OUTS);
  float*          Pa     = (float*)(ws + OFF_PA);
  float*          Pb     = (float*)(ws + OFF_PB);
  unsigned short* Bcat   = (unsigned short*)(ws + OFF_BCAT);
  float*          beta   = (float*)(ws + OFF_BETA);
  float*          parts  = (float*)(ws + OFF_PART);
  unsigned short* WsHi   = (unsigned short*)(ws + OFF_WSHI);
  unsigned short* WsLo   = (unsigned short*)(ws + OFF_WSLO);
  unsigned short* PHi    = (unsigned short*)(ws + OFF_PHI);
  unsigned short* PLo    = (unsigned short*)(ws + OFF_PLO);
  float*          Y      = (float*)(ws + OFF_Y);

  // weights -> bf16 (Bcat_1 = bf16(W_sani); hi/lo splits for the coef chain)
  k_cvtw<<<1024, 256, 0, stream>>>(W_in, W_sani, W_out, Win_b, Bcat, Wout_b);
  k_cvtWs<<<256, 256, 0, stream>>>(W_sani, WsHi, WsLo);
  k_gemm_emb<<<512, 256, 0, stream>>>(table, labels, Win_b, b_in, xt);
  k_copy<<<32, 256, 0, stream>>>((const uint4*)xt, (uint4*)outs, 8192);   // outs[0] = x_t[0]

  // bias chain beta_1..beta_4
  k_copy<<<1, 128, 0, stream>>>((const uint4*)b_sani, (uint4*)beta, 128);
  k_bias_step<<<512, 64, 0, stream>>>(W_sani, b_sani, beta,        beta + 512);
  k_bias_step<<<512, 64, 0, stream>>>(W_sani, b_sani, beta + 512,  beta + 1024);
  k_bias_step<<<512, 64, 0, stream>>>(W_sani, b_sani, beta + 1024, beta + 1536);

  // coefficient chain: P1 -> P2 -> P3 -> P4 (hi/lo-split bf16 GEMMs); Bcat_r via transpose
  k_trW <<<128, 256, 0, stream>>>(W_sani, Pa);                    // P1 (2 mats)
  k_cvtP<<<256, 256, 0, stream>>>(Pa, PHi, PLo, 65536);
  k_coef<<< 96, 256, 0, stream>>>(PHi, PLo, Pb, WsHi, WsLo, 1);   // P2 (3 mats)
  k_cvtP<<<384, 256, 0, stream>>>(Pb, PHi, PLo, 98304);
  k_trB <<<192, 256, 0, stream>>>(Pb, Bcat + 524288, 2);
  k_coef<<<128, 256, 0, stream>>>(PHi, PLo, Pa, WsHi, WsLo, 2);   // P3 (4 mats)
  k_cvtP<<<512, 256, 0, stream>>>(Pa, PHi, PLo, 131072);
  k_trB <<<256, 256, 0, stream>>>(Pa, Bcat + 1310720, 3);
  k_coef<<<160, 256, 0, stream>>>(PHi, PLo, Pb, WsHi, WsLo, 3);   // P4 (5 mats)
  k_trB <<<320, 256, 0, stream>>>(Pb, Bcat + 2359296, 4);

  // 16 multi-level steps (15 x m=4, 1 x m=3)
  const unsigned short* srcp = xt;
  for (int j = 1; j <= 16; ++j) {
    int L_prev = 4 * (j - 1);
    int m = (j == 16) ? 3 : 4;
    int nmain = 64 - (L_prev + m);
    int g = (nmain + 3) >> 2;          // slabs per s-group (4 s-groups)
    unsigned short* dstp = ((j - 1) & 1) ? lvl1 : lvl0;
    k_step<<<32 * g + (m - 1) * 8, 256, 0, stream>>>(srcp, dstp, outs, Bcat, beta,
                                                     L_prev, m, nmain, g);
    srcp = dstp;
  }

  k_gemm_out<<<512, 256, 0, stream>>>(outs, Wout_b, b_out, Y);
  k_loss<<<128, 256, 0, stream>>>(Y, table, labels, parts);
  k_final<<<1, 64, 0, stream>>>(parts, (float*)d_out);
}

// Round 10
// 628.742 us; speedup vs baseline: 3.5945x; 1.0992x over previous
//
#include <hip/hip_runtime.h>
#include <hip/hip_bf16.h>

typedef __attribute__((ext_vector_type(8))) short short8;
typedef __attribute__((ext_vector_type(4))) float floatx4;

#define NB 128      // batch N
#define LS 64       // seq L
#define HD 512      // hidden H
#define ED 512      // embed E
#define NH 65536    // NB*HD elements per s-slab
#define LDA 72      // LDS tile stride for reg-staged kernels (64 + 8 pad)
#define LDC 136     // LDS C-tile stride (128 + 8 pad)

// ws layout (byte offsets)
#define OFF_WIN    0ull          // W_in bf16   [512*512]
#define OFF_WOUT   524288ull     // W_out bf16  [512*512]
#define OFF_XT     1048576ull    // x_t bf16    [64][128][512]  (= level 0)
#define OFF_LVL0   9437184ull    // level ping  bf16 [64][128][512]
#define OFF_LVL1   17825792ull   // level pong  bf16 [64][128][512]
#define OFF_OUTS   26214400ull   // outs bf16   [64][128][512]
#define OFF_PA     34603008ull   // coef chain ping f32 (up to 5x 512x512)
#define OFF_PB     39845888ull   // coef chain pong f32
#define OFF_BCAT   45088768ull   // Bcat_1..4 bf16 concat (7 MB)
#define OFF_BETA   52428800ull   // beta_1..4 f32 [4][512]
#define OFF_PART   52436992ull   // partials f32 [128]
#define OFF_WSHI   52437504ull   // W_sani hi bf16 [512*1024] (1 MB)
#define OFF_WSLO   53486080ull   // W_sani lo bf16 (1 MB)
#define OFF_PHI    54534656ull   // P stage hi bf16 (<=5 mats, 2.62 MB)
#define OFF_PLO    57156096ull   // P stage lo bf16 (2.62 MB)
#define OFF_Y      OFF_LVL0      // Y f32 [8192][512] aliases lvl bufs after recurrence

static __device__ __forceinline__ unsigned short f2b(float f) {
  unsigned u = __float_as_uint(f);
  u += 0x7fffu + ((u >> 16) & 1u);   // round-to-nearest-even
  return (unsigned short)(u >> 16);
}
static __device__ __forceinline__ float b2f(unsigned short h) {
  return __uint_as_float(((unsigned)h) << 16);
}

// async global -> LDS, 16B per lane; LDS dest = wave-uniform base + lane*16
static __device__ __forceinline__ void gl_lds16(const unsigned short* g, unsigned short* l) {
  __builtin_amdgcn_global_load_lds(
      (const __attribute__((address_space(1))) void*)g,
      (__attribute__((address_space(3))) void*)l, 16, 0, 0);
}

// load 8 consecutive f32, produce bf16x8 packed (hi only; used for emb gather)
static __device__ __forceinline__ uint4 cvt8hi(const float* s) {
  floatx4 f0 = *(const floatx4*)s;
  floatx4 f1 = *(const floatx4*)(s + 4);
  float f[8] = {f0.x, f0.y, f0.z, f0.w, f1.x, f1.y, f1.z, f1.w};
  unsigned short b[8];
#pragma unroll
  for (int k = 0; k < 8; ++k) b[k] = f2b(f[k]);
  uint4 u;
  u.x = b[0] | ((unsigned)b[1] << 16); u.y = b[2] | ((unsigned)b[3] << 16);
  u.z = b[4] | ((unsigned)b[5] << 16); u.w = b[6] | ((unsigned)b[7] << 16);
  return u;
}

// ---- shared GEMM core (padded LDA=72): BM=64, BN=128, 256 threads (4 waves, 2x2) ----
__device__ __forceinline__ void gemm_core24(const unsigned short* As, const unsigned short* Bs,
                                            floatx4 acc[2][4], int wm, int wn, int lane) {
  const int rb = lane & 15;
  const int kg = (lane >> 4) * 8;
#pragma unroll
  for (int kk = 0; kk < 64; kk += 32) {
    short8 a[2], b[4];
#pragma unroll
    for (int i = 0; i < 2; ++i)
      a[i] = *(const short8*)&As[(wm * 32 + i * 16 + rb) * LDA + kk + kg];
#pragma unroll
    for (int j = 0; j < 4; ++j)
      b[j] = *(const short8*)&Bs[(wn * 64 + j * 16 + rb) * LDA + kk + kg];
#pragma unroll
    for (int i = 0; i < 2; ++i)
#pragma unroll
      for (int j = 0; j < 4; ++j)
        acc[i][j] = __builtin_amdgcn_mfma_f32_16x16x32_bf16(a[i], b[j], acc[i][j], 0, 0, 0);
  }
}

// ---- UNPADDED stride-64 core with XOR bank swizzle (for gload_lds-staged k_step).
//      LDS slot s of row r holds global slot s^(r&7); reading (kk+kg)^( (rb&7)*8 )
//      returns the ORIGINAL element -> bit-identical math, conflict-free banks. ----
__device__ __forceinline__ void gemm_core64s(const unsigned short* As, const unsigned short* Bs,
                                             floatx4 acc[2][4], int wm, int wn, int lane) {
  const int rb = lane & 15;
  const int kg = (lane >> 4) * 8;
  const int xv = (rb & 7) * 8;       // XOR swizzle, units of 8 shorts (16B)
#pragma unroll
  for (int kk = 0; kk < 64; kk += 32) {
    const int co = (kk + kg) ^ xv;   // kk+kg is a multiple of 8 -> pure slot XOR
    short8 a[2], b[4];
#pragma unroll
    for (int i = 0; i < 2; ++i)
      a[i] = *(const short8*)&As[(wm * 32 + i * 16 + rb) * 64 + co];
#pragma unroll
    for (int j = 0; j < 4; ++j)
      b[j] = *(const short8*)&Bs[(wn * 64 + j * 16 + rb) * 64 + co];
#pragma unroll
    for (int i = 0; i < 2; ++i)
#pragma unroll
      for (int j = 0; j < 4; ++j)
        acc[i][j] = __builtin_amdgcn_mfma_f32_16x16x32_bf16(a[i], b[j], acc[i][j], 0, 0, 0);
  }
}

__device__ __forceinline__ void stageA_bf16(unsigned short* As, const unsigned short* src, int tid) {
  int r = tid >> 3, kc = (tid & 7) * 8;
#pragma unroll
  for (int p = 0; p < 2; ++p)
    *(uint4*)&As[(r + p * 32) * LDA + kc] = *(const uint4*)(src + (size_t)(r + p * 32) * 512 + kc);
}

__device__ __forceinline__ void stageA_emb(unsigned short* As, const float* table,
                                           const int* labels, int m0, int k0, int tid) {
  int r = tid >> 3, kc = (tid & 7) * 8;
#pragma unroll
  for (int p = 0; p < 2; ++p) {
    int row = r + p * 32;
    const float* s = table + (size_t)labels[m0 + row] * ED + k0 + kc;
    *(uint4*)&As[row * LDA + kc] = cvt8hi(s);
  }
}

__device__ __forceinline__ void stageB(unsigned short* Bs, const unsigned short* src, int ldB, int tid) {
  int r = tid >> 3, kc = (tid & 7) * 8;
#pragma unroll
  for (int p = 0; p < 4; ++p)
    *(uint4*)&Bs[(r + p * 32) * LDA + kc] = *(const uint4*)(src + (size_t)(r + p * 32) * ldB + kc);
}

// ---- phase 1: x_t[l][n][h] = bf16( emb(labels) @ W_in^T + b_in ) ----
__global__ __launch_bounds__(256) void k_gemm_emb(const float* __restrict__ table,
                                                  const int* __restrict__ labels,
                                                  const unsigned short* __restrict__ Wb,
                                                  const float* __restrict__ bias,
                                                  unsigned short* __restrict__ xt) {
  __shared__ unsigned short As[64 * LDA];
  __shared__ unsigned short Bs[128 * LDA];
  int tid = threadIdx.x;
  int mtile = blockIdx.x >> 2, ntile = blockIdx.x & 3;
  int m0 = mtile * 64, n0 = ntile * 128;
  int lane = tid & 63, wave = tid >> 6, wm = wave >> 1, wn = wave & 1;
  floatx4 acc[2][4] = {};
  for (int k0 = 0; k0 < 512; k0 += 64) {
    stageA_emb(As, table, labels, m0, k0, tid);
    stageB(Bs, Wb + (size_t)n0 * 512 + k0, 512, tid);
    __syncthreads();
    gemm_core24(As, Bs, acc, wm, wn, lane);
    __syncthreads();
  }
  int rb = lane & 15, rg = (lane >> 4) * 4;
#pragma unroll
  for (int i = 0; i < 2; ++i)
#pragma unroll
    for (int j = 0; j < 4; ++j) {
      int col = n0 + wn * 64 + j * 16 + rb;
      float bv = bias[col];
#pragma unroll
      for (int reg = 0; reg < 4; ++reg) {
        int m = m0 + wm * 32 + i * 16 + rg + reg;
        int n = m >> 6, l = m & 63;
        xt[((size_t)l * NB + n) * HD + col] = f2b(acc[i][j][reg] + bv);
      }
    }
}

// ---- W_sani -> hi/lo bf16 split (same formula as the old inline cvt8) ----
__global__ __launch_bounds__(256) void k_cvtWs(const float* __restrict__ Ws,
                                               unsigned short* __restrict__ Hi,
                                               unsigned short* __restrict__ Lo) {
  int i = blockIdx.x * 256 + threadIdx.x;          // 8-float chunk, total 65536
  const float* s = Ws + (size_t)i * 8;
  unsigned short hb[8], lb[8];
#pragma unroll
  for (int k = 0; k < 8; ++k) {
    float f = s[k];
    unsigned short H = f2b(f);
    hb[k] = H; lb[k] = f2b(f - b2f(H));
  }
  uint4 h, l;
  h.x = hb[0] | ((unsigned)hb[1] << 16); h.y = hb[2] | ((unsigned)hb[3] << 16);
  h.z = hb[4] | ((unsigned)hb[5] << 16); h.w = hb[6] | ((unsigned)hb[7] << 16);
  l.x = lb[0] | ((unsigned)lb[1] << 16); l.y = lb[2] | ((unsigned)lb[3] << 16);
  l.z = lb[4] | ((unsigned)lb[5] << 16); l.w = lb[6] | ((unsigned)lb[7] << 16);
  *(uint4*)(Hi + (size_t)i * 8) = h;
  *(uint4*)(Lo + (size_t)i * 8) = l;
}

// ---- P stage f32 -> hi/lo bf16 ----
__global__ __launch_bounds__(256) void k_cvtP(const float* __restrict__ P,
                                              unsigned short* __restrict__ Hi,
                                              unsigned short* __restrict__ Lo, int n8) {
  int i = blockIdx.x * 256 + threadIdx.x;
  if (i >= n8) return;
  const float* s = P + (size_t)i * 8;
  unsigned short hb[8], lb[8];
#pragma unroll
  for (int k = 0; k < 8; ++k) {
    float f = s[k];
    unsigned short H = f2b(f);
    hb[k] = H; lb[k] = f2b(f - b2f(H));
  }
  uint4 h, l;
  h.x = hb[0] | ((unsigned)hb[1] << 16); h.y = hb[2] | ((unsigned)hb[3] << 16);
  h.z = hb[4] | ((unsigned)hb[5] << 16); h.w = hb[6] | ((unsigned)hb[7] << 16);
  l.x = lb[0] | ((unsigned)lb[1] << 16); l.y = lb[2] | ((unsigned)lb[3] << 16);
  l.z = lb[4] | ((unsigned)lb[5] << 16); l.w = lb[6] | ((unsigned)lb[7] << 16);
  *(uint4*)(Hi + (size_t)i * 8) = h;
  *(uint4*)(Lo + (size_t)i * 8) = l;
}

// ---- coefficient chain: P_{m+1,j} = gemm(P_{m,j}, W2) + gemm(P_{m,j-1}, W1),
//      pure-bf16 staged from precomputed hi/lo splits (bit-identical to old cvt8 path). ----
__global__ __launch_bounds__(256) void k_coef(const unsigned short* __restrict__ Phi,
                                              const unsigned short* __restrict__ Plo,
                                              float* __restrict__ Pout,
                                              const unsigned short* __restrict__ WsHi,
                                              const unsigned short* __restrict__ WsLo,
                                              int m) {
  __shared__ unsigned short As[64 * LDA];
  __shared__ unsigned short Bs[128 * LDA];
  int tid = threadIdx.x;
  int j = blockIdx.x >> 5, tile = blockIdx.x & 31;
  int k0r = (tile >> 2) * 64, n0 = (tile & 3) * 128;
  int lane = tid & 63, wave = tid >> 6, wm = wave >> 1, wn = wave & 1;
  floatx4 acc[2][4] = {};
  for (int term = 0; term < 2; ++term) {
    if (term == 0 && j > m) continue;
    if (term == 1 && j < 1) continue;
    const size_t pbase = (size_t)(term == 0 ? j : j - 1) * 262144;
    const int coloff = (term == 0) ? 512 : 0;   // term0: W2, term1: W1
    for (int v = 0; v < 3; ++v) {                // (hi,hi),(hi,lo),(lo,hi)
      const unsigned short* Asrc = (v == 2 ? Plo : Phi) + pbase;
      const unsigned short* Bsrc = (v == 1 ? WsLo : WsHi);
      for (int t0 = 0; t0 < 512; t0 += 64) {
        stageA_bf16(As, Asrc + (size_t)k0r * 512 + t0, tid);
        stageB(Bs, Bsrc + (size_t)n0 * 1024 + coloff + t0, 1024, tid);
        __syncthreads();
        gemm_core24(As, Bs, acc, wm, wn, lane);
        __syncthreads();
      }
    }
  }
  int rb = lane & 15, rg = (lane >> 4) * 4;
#pragma unroll
  for (int i = 0; i < 2; ++i)
#pragma unroll
    for (int jj = 0; jj < 4; ++jj) {
      int col = n0 + wn * 64 + jj * 16 + rb;
#pragma unroll
      for (int reg = 0; reg < 4; ++reg) {
        int row = wm * 32 + i * 16 + rg + reg;
        Pout[(size_t)j * 262144 + (size_t)(k0r + row) * 512 + col] = acc[i][jj][reg];
      }
    }
}

// ---- P_1 = {W2^T, W1^T} f32 (transpose of W_sani halves) ----
__global__ __launch_bounds__(256) void k_trW(const float* __restrict__ Ws,
                                             float* __restrict__ P1) {
  __shared__ float t[64][65];
  int mat = blockIdx.x >> 6, tile = blockIdx.x & 63;
  int a0 = (tile >> 3) * 64, b0 = (tile & 7) * 64;
  int coloff = (mat == 0) ? 512 : 0;   // P_{1,0}=W2^T, P_{1,1}=W1^T
  for (int pp = 0; pp < 16; ++pp) {
    int idx = pp * 256 + threadIdx.x, rr = idx >> 6, cc = idx & 63;
    t[rr][cc] = Ws[(size_t)(b0 + rr) * 1024 + coloff + a0 + cc];
  }
  __syncthreads();
  for (int pp = 0; pp < 16; ++pp) {
    int idx = pp * 256 + threadIdx.x, rr = idx >> 6, cc = idx & 63;
    P1[(size_t)mat * 262144 + (size_t)(a0 + rr) * 512 + b0 + cc] = t[cc][rr];
  }
}

// ---- Bcat_r[i][q*512+t] = A_{r,r-q}[i][t] = P_{r,r-q}[t][i], f32 -> bf16 ----
__global__ __launch_bounds__(256) void k_trB(const float* __restrict__ Pr,
                                             unsigned short* __restrict__ Bout,
                                             int r) {
  __shared__ float t[64][65];
  int q = blockIdx.x >> 6, tile = blockIdx.x & 63;
  int t0 = (tile >> 3) * 64, i0 = (tile & 7) * 64;
  const float* P = Pr + (size_t)(r - q) * 262144;
  int ldB = (r + 1) * 512;
  for (int pp = 0; pp < 16; ++pp) {
    int idx = pp * 256 + threadIdx.x, rr = idx >> 6, cc = idx & 63;
    t[rr][cc] = P[(size_t)(t0 + rr) * 512 + i0 + cc];
  }
  __syncthreads();
  for (int pp = 0; pp < 16; ++pp) {
    int idx = pp * 256 + threadIdx.x, rr = idx >> 6, cc = idx & 63;
    Bout[(size_t)(i0 + rr) * ldB + q * 512 + t0 + cc] = f2b(t[cc][rr]);
  }
}

// ---- beta_{r+1}[i] = sum_k (W1+W2)[i][k] * beta_r[k] + b[i] ----
__global__ __launch_bounds__(64) void k_bias_step(const float* __restrict__ Ws,
                                                  const float* __restrict__ b,
                                                  const float* __restrict__ bprev,
                                                  float* __restrict__ bout) {
  int i = blockIdx.x, t = threadIdx.x;
  float p = 0.f;
  for (int k = t; k < 512; k += 64)
    p += (Ws[(size_t)i * 1024 + k] + Ws[(size_t)i * 1024 + 512 + k]) * bprev[k];
#pragma unroll
  for (int off = 32; off > 0; off >>= 1) p += __shfl_down(p, off, 64);
  if (t == 0) bout[i] = p + b[i];
}

// ---- phase 2: one multi-level step. BM=64, BN=128, 256 threads (4 waves, 2x2).
//      2-phase template: STAGE(next via global_load_lds w16) || MFMA(cur), one barrier
//      per K-step. Unpadded linear LDS + BOTH-SIDES XOR bank swizzle (rule #21):
//      global source column pre-swizzled with (tid&7)^(row&7); ds_read applies the
//      same involution -> identical operands, conflict-free banks.
//      XCD-affinity mapping + full-line epilogue. Bit-identical numerics. ----
__global__ __launch_bounds__(256) void k_step(const unsigned short* __restrict__ src,
                                              unsigned short* __restrict__ dst,
                                              unsigned short* __restrict__ outs,
                                              const unsigned short* __restrict__ Bcat,
                                              const float* __restrict__ beta,
                                              int L_prev, int m, int nmain, int g) {
  __shared__ unsigned short lds[24576];   // A0[4096] A1[4096] B0[8192] B1[8192] = 48 KB
  unsigned short* const A0 = lds;
  unsigned short* const A1 = lds + 4096;
  unsigned short* const B0 = lds + 8192;
  unsigned short* const B1 = lds + 16384;
  const int tid = threadIdx.x, bid = blockIdx.x;
  const int mainWG = 32 * g;   // 8 XCDs x g slabs x 4 (2 nb0 x 2 n-panels)
  int r, s, nb0, n0;
  if (bid < mainWG) {
    const int xcd = bid & 7, w = bid >> 3;        // dispatch round-robin -> XCD
    const int sgrp = xcd >> 1, ngrp = xcd & 1;
    const int s_rel = sgrp * g + (w >> 2);
    if (s_rel >= nmain) return;                    // uniform block exit (pre-barrier)
    const int sub2 = w & 3;
    nb0 = (sub2 >> 1) * 64;
    n0 = (ngrp * 2 + (sub2 & 1)) * 128;
    r = m; s = L_prev + m + s_rel;
  } else {
    const int db = bid - mainWG;
    r = 1 + (db >> 3);
    const int sub = db & 7;
    nb0 = (sub >> 2) * 64; n0 = (sub & 3) * 128;
    s = L_prev + r;
  }
  const int ldB = (r + 1) * 512;
  const unsigned short* Bp = Bcat + (size_t)262144 * (((r - 1) * (r + 2)) >> 1);
  const unsigned short* abase = src + (size_t)(s - r) * NH + (size_t)nb0 * HD;
  const float* bet = beta + (size_t)(r - 1) * 512;
  const int nk = (r + 1) * 8;        // always even (16,24,32,40)
  const int lane = tid & 63, wave = tid >> 6, wm = wave >> 1, wn = wave & 1;
  const int rr_ = tid >> 3;
  const int kcs = (((tid & 7) ^ ((tid >> 3) & 7))) * 8;  // swizzled source column

  floatx4 acc[2][4] = {};

  // STAGE: 6 global_load_lds calls fill A (8KB) + B (16KB) of one buffer.
  // LDS dest linear (lane*16); source column uses kcs so LDS slot s of row r
  // holds global slot s^(r&7). All staged rows are == rr_ (mod 8).
#define STAGE(Ab, Bb, kcol)                                                          \
  { int q_ = (kcol) >> 9, ac_ = (kcol) & 511;                                        \
    const unsigned short* a0_ = abase + (size_t)q_ * NH + ac_;                       \
    unsigned short* lA = (Ab) + (tid >> 6) * 512;                                    \
    unsigned short* lB = (Bb) + (tid >> 6) * 512;                                    \
    gl_lds16(a0_ + (size_t)rr_ * HD + kcs, lA);                                      \
    gl_lds16(a0_ + (size_t)(rr_ + 32) * HD + kcs, lA + 2048);                        \
    gl_lds16(Bp + (size_t)(n0 + rr_) * ldB + (kcol) + kcs, lB);                      \
    gl_lds16(Bp + (size_t)(n0 + rr_ + 32) * ldB + (kcol) + kcs, lB + 2048);          \
    gl_lds16(Bp + (size_t)(n0 + rr_ + 64) * ldB + (kcol) + kcs, lB + 4096);          \
    gl_lds16(Bp + (size_t)(n0 + rr_ + 96) * ldB + (kcol) + kcs, lB + 6144); }

  STAGE(A0, B0, 0)
  __syncthreads();                     // drain prologue loads
  for (int k = 0; k < nk; k += 2) {
    if (k + 1 < nk) STAGE(A1, B1, (k + 1) * 64)   // prefetch hides under MFMA
    gemm_core64s(A0, B0, acc, wm, wn, lane);
    __syncthreads();                               // drain prefetch + WAR-protect A0/B0
    if (k + 2 < nk) STAGE(A0, B0, (k + 2) * 64)
    gemm_core64s(A1, B1, acc, wm, wn, lane);
    __syncthreads();
  }
#undef STAGE

  // ---- epilogue: stage C (64x128 bf16) in LDS, then full-line stores ----
  unsigned short* Ct = lds;            // 64 x LDC = 8704 shorts <= 24576
  const int rbc = lane & 15, rg = (lane >> 4) * 4;
#pragma unroll
  for (int i = 0; i < 2; ++i)
#pragma unroll
    for (int j = 0; j < 4; ++j) {
      int col = wn * 64 + j * 16 + rbc;            // 0..127 local
      float bv = bet[n0 + col];
#pragma unroll
      for (int reg = 0; reg < 4; ++reg) {
        int row = wm * 32 + i * 16 + rg + reg;     // 0..63 local
        Ct[row * LDC + col] = f2b(acc[i][j][reg] + bv);
      }
    }
  __syncthreads();
  const bool wdst = (r == m);
  const bool wout = (r < m) || (s == L_prev + m);  // outs[li] = h(li,li)
  unsigned short* d1 = dst  + (size_t)s * NH + (size_t)nb0 * HD + n0;
  unsigned short* d2 = outs + (size_t)s * NH + (size_t)nb0 * HD + n0;
  const int lrow = tid >> 4, lcol = (tid & 15) * 8;  // 16 thr x 16B = 256B/row
#pragma unroll
  for (int sweep = 0; sweep < 4; ++sweep) {
    int row = sweep * 16 + lrow;
    uint4 v = *(const uint4*)&Ct[row * LDC + lcol];
    if (wdst) *(uint4*)(d1 + (size_t)row * HD + lcol) = v;
    if (wout) *(uint4*)(d2 + (size_t)row * HD + lcol) = v;
  }
}

// ---- phase 3: Y = outs_flat @ W_out^T + b_out  (fp32 out) ----
__global__ __launch_bounds__(256) void k_gemm_out(const unsigned short* __restrict__ outs,
                                                  const unsigned short* __restrict__ Wb,
                                                  const float* __restrict__ bias,
                                                  float* __restrict__ Y) {
  __shared__ unsigned short As[64 * LDA];
  __shared__ unsigned short Bs[128 * LDA];
  int tid = threadIdx.x;
  int mtile = blockIdx.x >> 2, ntile = blockIdx.x & 3;
  int m0 = mtile * 64, n0 = ntile * 128;
  int lane = tid & 63, wave = tid >> 6, wm = wave >> 1, wn = wave & 1;
  floatx4 acc[2][4] = {};
  for (int k0 = 0; k0 < 512; k0 += 64) {
    stageA_bf16(As, outs + (size_t)m0 * 512 + k0, tid);
    stageB(Bs, Wb + (size_t)n0 * 512 + k0, 512, tid);
    __syncthreads();
    gemm_core24(As, Bs, acc, wm, wn, lane);
    __syncthreads();
  }
  int rb = lane & 15, rg = (lane >> 4) * 4;
#pragma unroll
  for (int i = 0; i < 2; ++i)
#pragma unroll
    for (int j = 0; j < 4; ++j) {
      int col = n0 + wn * 64 + j * 16 + rb;
      float bv = bias[col];
#pragma unroll
      for (int reg = 0; reg < 4; ++reg) {
        int row = m0 + wm * 32 + i * 16 + rg + reg;
        Y[(size_t)row * 512 + col] = acc[i][j][reg] + bv;
      }
    }
}

// ---- weights fp32 -> bf16: W_in, W_sani (-> Bcat_1), W_out ----
__global__ __launch_bounds__(256) void k_cvtw(const float* __restrict__ Win,
                                              const float* __restrict__ Wsani,
                                              const float* __restrict__ Wout,
                                              unsigned short* __restrict__ dWin,
                                              unsigned short* __restrict__ dBcat1,
                                              unsigned short* __restrict__ dWout) {
  int i = blockIdx.x * 256 + threadIdx.x;  // float4 index, total 262144
  const float* src;
  unsigned short* dst;
  int off;
  if (i < 65536)       { src = Win;   dst = dWin;   off = i; }
  else if (i < 196608) { src = Wsani; dst = dBcat1; off = i - 65536; }
  else                 { src = Wout;  dst = dWout;  off = i - 196608; }
  floatx4 v = *(const floatx4*)(src + (size_t)off * 4);
  uint2 u;
  u.x = (unsigned)f2b(v.x) | ((unsigned)f2b(v.y) << 16);
  u.y = (unsigned)f2b(v.z) | ((unsigned)f2b(v.w) << 16);
  *(uint2*)(dst + (size_t)off * 4) = u;
}

__global__ void k_copy(const uint4* __restrict__ src, uint4* __restrict__ dst, int n) {
  int i = blockIdx.x * blockDim.x + threadIdx.x;
  if (i < n) dst[i] = src[i];
}

// ---- loss: per n, column-softmax over 64 consecutive Y rows, dot with emb ----
__global__ __launch_bounds__(256) void k_loss(const float* __restrict__ Y,
                                              const float* __restrict__ table,
                                              const int* __restrict__ labels,
                                              float* __restrict__ partials) {
  int n = blockIdx.x, tid = threadIdx.x;
  float total = 0.f;
#pragma unroll
  for (int e2 = 0; e2 < 2; ++e2) {
    int e = e2 * 256 + tid;
    float mx = -1e30f;
    for (int l = 0; l < 64; ++l)
      mx = fmaxf(mx, Y[(size_t)(n * 64 + l) * 512 + e]);
    float se = 0.f;
    for (int l = 0; l < 64; ++l)
      se += expf(Y[(size_t)(n * 64 + l) * 512 + e] - mx);
    float lse = mx + logf(se);
    for (int l = 0; l < 64; ++l) {
      float embv = table[(size_t)labels[n * 64 + l] * ED + e];
      total += embv * (Y[(size_t)(n * 64 + l) * 512 + e] - lse);
    }
  }
  __shared__ float red[256];
  red[tid] = total;
  __syncthreads();
  for (int s2 = 128; s2 > 0; s2 >>= 1) {
    if (tid < s2) red[tid] += red[tid + s2];
    __syncthreads();
  }
  if (tid == 0) partials[n] = red[0];
}

__global__ void k_final(const float* __restrict__ partials, float* __restrict__ out) {
  if (threadIdx.x == 0) {
    double s = 0.0;
    for (int i = 0; i < 128; ++i) s += (double)partials[i];
    out[0] = (float)(-s / 65536.0);
  }
}

extern "C" void kernel_launch(void* const* d_in, const int* in_sizes, int n_in,
                              void* d_out, int out_size, void* d_ws, size_t ws_size,
                              hipStream_t stream) {
  const int*   labels = (const int*)d_in[0];
  const float* table  = (const float*)d_in[1];
  const float* W_in   = (const float*)d_in[2];
  const float* b_in   = (const float*)d_in[3];
  const float* W_sani = (const float*)d_in[4];
  const float* b_sani = (const float*)d_in[5];
  const float* W_out  = (const float*)d_in[6];
  const float* b_out  = (const float*)d_in[7];

  char* ws = (char*)d_ws;
  unsigned short* Win_b  = (unsigned short*)(ws + OFF_WIN);
  unsigned short* Wout_b = (unsigned short*)(ws + OFF_WOUT);
  unsigned short* xt     = (unsigned short*)(ws + OFF_XT);
  unsigned short* lvl0   = (unsigned short*)(ws + OFF_LVL0);
  unsigned short* lvl1   = (unsigned short*)(ws + OFF_LVL1);
  unsigned short* outs   = (unsigned short*)(ws + OFF_OUTS);
  float*          Pa     = (float*)(ws + OFF_PA);
  float*          Pb     = (float*)(ws + OFF_PB);
  unsigned short* Bcat   = (unsigned short*)(ws + OFF_BCAT);
  float*          beta   = (float*)(ws + OFF_BETA);
  float*          parts  = (float*)(ws + OFF_PART);
  unsigned short* WsHi   = (unsigned short*)(ws + OFF_WSHI);
  unsigned short* WsLo   = (unsigned short*)(ws + OFF_WSLO);
  unsigned short* PHi    = (unsigned short*)(ws + OFF_PHI);
  unsigned short* PLo    = (unsigned short*)(ws + OFF_PLO);
  float*          Y      = (float*)(ws + OFF_Y);

  // weights -> bf16 (Bcat_1 = bf16(W_sani); hi/lo splits for the coef chain)
  k_cvtw<<<1024, 256, 0, stream>>>(W_in, W_sani, W_out, Win_b, Bcat, Wout_b);
  k_cvtWs<<<256, 256, 0, stream>>>(W_sani, WsHi, WsLo);
  k_gemm_emb<<<512, 256, 0, stream>>>(table, labels, Win_b, b_in, xt);
  k_copy<<<32, 256, 0, stream>>>((const uint4*)xt, (uint4*)outs, 8192);   // outs[0] = x_t[0]

  // bias chain beta_1..beta_4
  k_copy<<<1, 128, 0, stream>>>((const uint4*)b_sani, (uint4*)beta, 128);
  k_bias_step<<<512, 64, 0, stream>>>(W_sani, b_sani, beta,        beta + 512);
  k_bias_step<<<512, 64, 0, stream>>>(W_sani, b_sani, beta + 512,  beta + 1024);
  k_bias_step<<<512, 64, 0, stream>>>(W_sani, b_sani, beta + 1024, beta + 1536);

  // coefficient chain: P1 -> P2 -> P3 -> P4 (hi/lo-split bf16 GEMMs); Bcat_r via transpose
  k_trW <<<128, 256, 0, stream>>>(W_sani, Pa);                    // P1 (2 mats)
  k_cvtP<<<256, 256, 0, stream>>>(Pa, PHi, PLo, 65536);
  k_coef<<< 96, 256, 0, stream>>>(PHi, PLo, Pb, WsHi, WsLo, 1);   // P2 (3 mats)
  k_cvtP<<<384, 256, 0, stream>>>(Pb, PHi, PLo, 98304);
  k_trB <<<192, 256, 0, stream>>>(Pb, Bcat + 524288, 2);
  k_coef<<<128, 256, 0, stream>>>(PHi, PLo, Pa, WsHi, WsLo, 2);   // P3 (4 mats)
  k_cvtP<<<512, 256, 0, stream>>>(Pa, PHi, PLo, 131072);
  k_trB <<<256, 256, 0, stream>>>(Pa, Bcat + 1310720, 3);
  k_coef<<<160, 256, 0, stream>>>(PHi, PLo, Pb, WsHi, WsLo, 3);   // P4 (5 mats)
  k_trB <<<320, 256, 0, stream>>>(Pb, Bcat + 2359296, 4);

  // 16 multi-level steps (15 x m=4, 1 x m=3)
  const unsigned short* srcp = xt;
  for (int j = 1; j <= 16; ++j) {
    int L_prev = 4 * (j - 1);
    int m = (j == 16) ? 3 : 4;
    int nmain = 64 - (L_prev + m);
    int g = (nmain + 3) >> 2;          // slabs per s-group (4 s-groups)
    unsigned short* dstp = ((j - 1) & 1) ? lvl1 : lvl0;
    k_step<<<32 * g + (m - 1) * 8, 256, 0, stream>>>(srcp, dstp, outs, Bcat, beta,
                                                     L_prev, m, nmain, g);
    srcp = dstp;
  }

  k_gemm_out<<<512, 256, 0, stream>>>(outs, Wout_b, b_out, Y);
  k_loss<<<128, 256, 0, stream>>>(Y, table, labels, parts);
  k_final<<<1, 64, 0, stream>>>(parts, (float*)d_out);
}